// Round 1
// baseline (3079.479 us; speedup 1.0000x reference)
//
#include <hip/hip_runtime.h>
#include <math.h>

#define HW 16384
#define WIDTH 128

__device__ __forceinline__ float wave_sum(float v) {
#pragma unroll
  for (int o = 32; o > 0; o >>= 1) v += __shfl_down(v, o, 64);
  return v;
}

// ---------------- fi = mean over H,W ----------------
__global__ __launch_bounds__(256) void k_mean(const float* __restrict__ x,
                                              float* __restrict__ fi) {
  __shared__ float sm[4];
  int nc = blockIdx.x;  // 0..767
  const float4* p = (const float4*)(x + (size_t)nc * HW);
  float s = 0.f;
  for (int i = threadIdx.x; i < HW / 4; i += 256) {
    float4 v = p[i];
    s += (v.x + v.y) + (v.z + v.w);
  }
  s = wave_sum(s);
  int wid = threadIdx.x >> 6, lane = threadIdx.x & 63;
  if (!lane) sm[wid] = s;
  __syncthreads();
  if (!threadIdx.x) fi[nc] = (sm[0] + sm[1] + sm[2] + sm[3]) * (1.f / 16384.f);
}

// ---------------- dynamic filter: 1x1 conv -> GN(4 groups) -> softmax(9) ----------------
__global__ __launch_bounds__(256) void k_filter(const float* __restrict__ fi,
                                                const float* __restrict__ cf_w,
                                                const float* __restrict__ gnf_s,
                                                const float* __restrict__ gnf_b,
                                                float* __restrict__ filt) {
  int n = blockIdx.x;
  int t = threadIdx.x;
  __shared__ __align__(16) float sfi[96];
  __shared__ float sfw[864];
  __shared__ float gstat[8];
  if (t < 96) sfi[t] = fi[n * 96 + t];
  __syncthreads();
  for (int oc = t; oc < 864; oc += 256) {
    const float4* wr = (const float4*)(cf_w + (size_t)oc * 96);
    const float4* fr = (const float4*)sfi;
    float a = 0.f;
#pragma unroll
    for (int q = 0; q < 24; q++) {
      float4 w4 = wr[q];
      float4 f4 = fr[q];
      a += w4.x * f4.x + w4.y * f4.y + w4.z * f4.z + w4.w * f4.w;
    }
    sfw[oc] = a;
  }
  __syncthreads();
  if (t < 4) {
    float s = 0.f, ss = 0.f;
    for (int i = 0; i < 216; i++) {
      float v = sfw[t * 216 + i];
      s += v;
      ss += v * v;
    }
    float m = s * (1.f / 216.f);
    float var = ss * (1.f / 216.f) - m * m;
    gstat[t * 2] = m;
    gstat[t * 2 + 1] = rsqrtf(var + 1e-5f);
  }
  __syncthreads();
  for (int oc = t; oc < 864; oc += 256) {
    int g = oc / 216;
    sfw[oc] = (sfw[oc] - gstat[g * 2]) * gstat[g * 2 + 1] * gnf_s[oc] + gnf_b[oc];
  }
  __syncthreads();
  if (t < 96) {
    float v[9], mx = -1e30f;
#pragma unroll
    for (int k = 0; k < 9; k++) {
      v[k] = sfw[t * 9 + k];
      mx = fmaxf(mx, v[k]);
    }
    float s = 0.f;
#pragma unroll
    for (int k = 0; k < 9; k++) {
      v[k] = expf(v[k] - mx);
      s += v[k];
    }
    float inv = 1.f / s;
#pragma unroll
    for (int k = 0; k < 9; k++) filt[((size_t)n * 96 + t) * 9 + k] = v[k] * inv;
  }
}

// ---------------- involution (reflect pad, taps {-2,0,2}) + high = x - low ----------------
__global__ __launch_bounds__(256) void k_invol(const float* __restrict__ x,
                                               const float* __restrict__ filt,
                                               float* __restrict__ low,
                                               float* __restrict__ high) {
  int nc = blockIdx.y;
  const float* xp = x + (size_t)nc * HW;
  const float* fp = filt + (size_t)nc * 9;
  float f[9];
#pragma unroll
  for (int k = 0; k < 9; k++) f[k] = fp[k];
  int idx = blockIdx.x * 256 + threadIdx.x;
  int y = idx >> 7, xx = idx & 127;
  int ry[3], rx[3];
#pragma unroll
  for (int d = 0; d < 3; d++) {
    int p = y + 2 * d - 2;
    if (p < 0) p = -p;
    if (p > 127) p = 254 - p;
    ry[d] = p;
    int q = xx + 2 * d - 2;
    if (q < 0) q = -q;
    if (q > 127) q = 254 - q;
    rx[d] = q;
  }
  float acc = 0.f;
#pragma unroll
  for (int i = 0; i < 3; i++)
#pragma unroll
    for (int j = 0; j < 3; j++) acc = fmaf(f[i * 3 + j], xp[ry[i] * WIDTH + rx[j]], acc);
  float xv = xp[idx];
  size_t o = (size_t)nc * HW + idx;
  low[o] = acc;
  high[o] = xv - acc;
}

// ---------------- generic 1x1 conv (+bias, optional PReLU) ----------------
template <int CIN, int COUT, bool PRELU>
__global__ __launch_bounds__(256) void k_conv1x1(const float* __restrict__ in,
                                                 const float* __restrict__ w,
                                                 const float* __restrict__ b,
                                                 const float* __restrict__ pr,
                                                 float* __restrict__ out) {
  int n = blockIdx.y;
  int pix = blockIdx.x * 256 + threadIdx.x;
  const float* ip = in + (size_t)n * CIN * HW + pix;
  float acc[COUT];
#pragma unroll
  for (int o = 0; o < COUT; o++) acc[o] = b[o];
  for (int c = 0; c < CIN; c += 4) {
    float v0 = ip[(size_t)c * HW];
    float v1 = ip[(size_t)(c + 1) * HW];
    float v2 = ip[(size_t)(c + 2) * HW];
    float v3 = ip[(size_t)(c + 3) * HW];
#pragma unroll
    for (int o = 0; o < COUT; o++) {
      float4 wv = *(const float4*)(w + (size_t)o * CIN + c);
      acc[o] = fmaf(v0, wv.x, acc[o]);
      acc[o] = fmaf(v1, wv.y, acc[o]);
      acc[o] = fmaf(v2, wv.z, acc[o]);
      acc[o] = fmaf(v3, wv.w, acc[o]);
    }
  }
  float a = PRELU ? pr[0] : 0.f;
  float* op = out + (size_t)n * COUT * HW + pix;
#pragma unroll
  for (int o = 0; o < COUT; o++) {
    float v = acc[o];
    if (PRELU) v = v >= 0.f ? v : a * v;
    op[(size_t)o * HW] = v;
  }
}

// ---------------- depthwise 3x3, zero pad = dilation ----------------
template <int DILA>
__global__ __launch_bounds__(256) void k_dw3x3(const float* __restrict__ in,
                                               const float* __restrict__ w,
                                               const float* __restrict__ b,
                                               float* __restrict__ out) {
  int ncz = blockIdx.y;  // n*24+c
  int c = ncz % 24;
  float wt[9];
#pragma unroll
  for (int k = 0; k < 9; k++) wt[k] = w[c * 9 + k];
  float acc = b[c];
  int pix = blockIdx.x * 256 + threadIdx.x;
  int y = pix >> 7, xx = pix & 127;
  const float* ip = in + (size_t)ncz * HW;
#pragma unroll
  for (int i = 0; i < 3; i++) {
    int yy = y + DILA * (i - 1);
    if (yy < 0 || yy >= 128) continue;
#pragma unroll
    for (int j = 0; j < 3; j++) {
      int xj = xx + DILA * (j - 1);
      if (xj < 0 || xj >= 128) continue;
      acc = fmaf(wt[i * 3 + j], ip[yy * WIDTH + xj], acc);
    }
  }
  out[(size_t)ncz * HW + pix] = acc;
}

// ---------------- GN stats for high: partial sums (atomic) ----------------
__global__ __launch_bounds__(256) void k_gnhigh_part(const float* __restrict__ h,
                                                     float* __restrict__ stats) {
  int ng = blockIdx.x;  // n*4+g, region = 24*HW contiguous
  const float4* p = (const float4*)(h + (size_t)ng * 393216 + (size_t)blockIdx.y * 49152);
  float s = 0.f, ss = 0.f;
  for (int i = threadIdx.x; i < 12288; i += 256) {
    float4 v = p[i];
    s += (v.x + v.y) + (v.z + v.w);
    ss += (v.x * v.x + v.y * v.y) + (v.z * v.z + v.w * v.w);
  }
  s = wave_sum(s);
  ss = wave_sum(ss);
  __shared__ float sm[8];
  int wid = threadIdx.x >> 6, lane = threadIdx.x & 63;
  if (!lane) {
    sm[wid] = s;
    sm[4 + wid] = ss;
  }
  __syncthreads();
  if (!threadIdx.x) {
    atomicAdd(&stats[ng * 2], sm[0] + sm[1] + sm[2] + sm[3]);
    atomicAdd(&stats[ng * 2 + 1], sm[4] + sm[5] + sm[6] + sm[7]);
  }
}

// ---------------- finalize GN stats: sum,sumsq -> mean,invstd ----------------
__global__ void k_gnfin(float* stats, float inv_cnt) {
  int i = threadIdx.x;  // 32 = n*groups
  float s = stats[i * 2], ss = stats[i * 2 + 1];
  float m = s * inv_cnt;
  float var = ss * inv_cnt - m * m;
  stats[i * 2] = m;
  stats[i * 2 + 1] = rsqrtf(var + 1e-5f);
}

// ---------------- hb: GN->leaky fused, 3x3 conv 96->96, +bias +residual ----------------
__global__ __launch_bounds__(256) void k_hbconv(const float* __restrict__ high,
                                                const float* __restrict__ hstats,
                                                const float* __restrict__ gs,
                                                const float* __restrict__ gb,
                                                const float* __restrict__ w,
                                                const float* __restrict__ bias,
                                                float* __restrict__ out) {
  // grid: (32 tiles [8y x 4x of 16x32], 4 oc-groups, 8 n); block 256
  __shared__ float stile[8 * 18 * 34];  // 8 ch chunk, halo 1
  int tid = threadIdx.x;
  int n = blockIdx.z;
  int ocg = blockIdx.y;
  int ty = blockIdx.x >> 2, tx = blockIdx.x & 3;
  int y0 = ty * 16, x0 = tx * 32;
  float hm[4], hi[4];
#pragma unroll
  for (int g = 0; g < 4; g++) {
    hm[g] = hstats[(n * 4 + g) * 2];
    hi[g] = hstats[(n * 4 + g) * 2 + 1];
  }
  float acc0[24], acc1[24];
#pragma unroll
  for (int o = 0; o < 24; o++) {
    acc0[o] = 0.f;
    acc1[o] = 0.f;
  }
  int px = tid & 31, py = tid >> 5;  // pixels (py,px) and (py+8,px) of 16x32 tile
  for (int cc = 0; cc < 12; cc++) {
    __syncthreads();
    for (int idx = tid; idx < 8 * 18 * 34; idx += 256) {
      int cl = idx / (18 * 34);
      int rem = idx - cl * (18 * 34);
      int ly = rem / 34, lx = rem - ly * 34;
      int gy = y0 + ly - 1, gx = x0 + lx - 1;
      int ca = cc * 8 + cl;
      float v = 0.f;
      if ((unsigned)gy < 128u && (unsigned)gx < 128u) {
        int g = ca / 24;
        float raw = high[((size_t)(n * 96 + ca)) * HW + gy * WIDTH + gx];
        float hh = (raw - hm[g]) * hi[g] * gs[ca] + gb[ca];
        v = hh >= 0.f ? hh : 0.01f * hh;
      }
      stile[idx] = v;
    }
    __syncthreads();
#pragma unroll
    for (int cl = 0; cl < 8; cl++) {
      const float* wrow = w + ((size_t)(ocg * 24) * 96 + (cc * 8 + cl)) * 9;
#pragma unroll
      for (int t9 = 0; t9 < 9; t9++) {
        int i = t9 / 3, j = t9 - i * 3;
        float a0 = stile[(cl * 18 + py + i) * 34 + px + j];
        float a1 = stile[(cl * 18 + py + 8 + i) * 34 + px + j];
#pragma unroll
        for (int o = 0; o < 24; o++) {
          float wv = wrow[(size_t)o * 864 + t9];  // block-uniform -> s_load
          acc0[o] = fmaf(a0, wv, acc0[o]);
          acc1[o] = fmaf(a1, wv, acc1[o]);
        }
      }
    }
  }
  int gy0 = y0 + py, gy1 = y0 + py + 8, gx = x0 + px;
#pragma unroll
  for (int o = 0; o < 24; o++) {
    int oc = ocg * 24 + o;
    size_t base = (size_t)(n * 96 + oc) * HW;
    float b = bias[oc];
    out[base + gy0 * WIDTH + gx] = acc0[o] + b + high[base + gy0 * WIDTH + gx];
    out[base + gy1 * WIDTH + gx] = acc1[o] + b + high[base + gy1 * WIDTH + gx];
  }
}

// ---------------- ff1: 1x1 192->192 (concat input), + GN stats atomic ----------------
__global__ __launch_bounds__(256) void k_ff1(const float* __restrict__ elow,
                                             const float* __restrict__ ehigh,
                                             const float* __restrict__ w,
                                             const float* __restrict__ bias,
                                             float* __restrict__ t,
                                             float* __restrict__ ffstats) {
  int n = blockIdx.z, half = blockIdx.y;
  int pix = blockIdx.x * 256 + threadIdx.x;
  float acc[96];
#pragma unroll
  for (int o = 0; o < 96; o++) acc[o] = 0.f;
  const float* ilow = elow + (size_t)n * 96 * HW + pix;
  const float* ihigh = ehigh + (size_t)n * 96 * HW + pix;
  const float* wb = w + (size_t)half * 96 * 192;
  for (int c = 0; c < 96; c += 4) {
    float v0 = ilow[(size_t)c * HW], v1 = ilow[(size_t)(c + 1) * HW];
    float v2 = ilow[(size_t)(c + 2) * HW], v3 = ilow[(size_t)(c + 3) * HW];
#pragma unroll
    for (int o = 0; o < 96; o++) {
      float4 wv = *(const float4*)(wb + (size_t)o * 192 + c);
      acc[o] = fmaf(v0, wv.x, acc[o]);
      acc[o] = fmaf(v1, wv.y, acc[o]);
      acc[o] = fmaf(v2, wv.z, acc[o]);
      acc[o] = fmaf(v3, wv.w, acc[o]);
    }
  }
  for (int c = 0; c < 96; c += 4) {
    float v0 = ihigh[(size_t)c * HW], v1 = ihigh[(size_t)(c + 1) * HW];
    float v2 = ihigh[(size_t)(c + 2) * HW], v3 = ihigh[(size_t)(c + 3) * HW];
#pragma unroll
    for (int o = 0; o < 96; o++) {
      float4 wv = *(const float4*)(wb + (size_t)o * 192 + 96 + c);
      acc[o] = fmaf(v0, wv.x, acc[o]);
      acc[o] = fmaf(v1, wv.y, acc[o]);
      acc[o] = fmaf(v2, wv.z, acc[o]);
      acc[o] = fmaf(v3, wv.w, acc[o]);
    }
  }
  float s0 = 0.f, ss0 = 0.f, s1 = 0.f, ss1 = 0.f;
  float* tp = t + ((size_t)n * 192 + half * 96) * HW + pix;
#pragma unroll
  for (int o = 0; o < 96; o++) {
    float v = acc[o] + bias[half * 96 + o];
    tp[(size_t)o * HW] = v;
    if (o < 48) {
      s0 += v;
      ss0 += v * v;
    } else {
      s1 += v;
      ss1 += v * v;
    }
  }
  s0 = wave_sum(s0);
  ss0 = wave_sum(ss0);
  s1 = wave_sum(s1);
  ss1 = wave_sum(ss1);
  __shared__ float sred[4][4];
  int wid = threadIdx.x >> 6, lane = threadIdx.x & 63;
  if (!lane) {
    sred[wid][0] = s0;
    sred[wid][1] = ss0;
    sred[wid][2] = s1;
    sred[wid][3] = ss1;
  }
  __syncthreads();
  if (threadIdx.x < 4) {
    int v = threadIdx.x;
    float tot = sred[0][v] + sred[1][v] + sred[2][v] + sred[3][v];
    atomicAdd(&ffstats[(n * 4 + half * 2 + (v >> 1)) * 2 + (v & 1)], tot);
  }
}

// ---------------- ff2: GN->gelu(exact) fused, 1x1 192->96 ----------------
__global__ __launch_bounds__(256) void k_ff2(const float* __restrict__ t,
                                             const float* __restrict__ ffstats,
                                             const float* __restrict__ gs,
                                             const float* __restrict__ gb,
                                             const float* __restrict__ w,
                                             const float* __restrict__ bias,
                                             float* __restrict__ out) {
  int n = blockIdx.y;
  int pix = blockIdx.x * 256 + threadIdx.x;
  float acc[96];
#pragma unroll
  for (int o = 0; o < 96; o++) acc[o] = bias[o];
  const float* tp = t + (size_t)n * 192 * HW + pix;
  float fm[4], fv[4];
#pragma unroll
  for (int g = 0; g < 4; g++) {
    fm[g] = ffstats[(n * 4 + g) * 2];
    fv[g] = ffstats[(n * 4 + g) * 2 + 1];
  }
  for (int c = 0; c < 192; c += 4) {
    int g = c / 48;
    float v[4];
#pragma unroll
    for (int q = 0; q < 4; q++) {
      float raw = tp[(size_t)(c + q) * HW];
      float z = (raw - fm[g]) * fv[g] * gs[c + q] + gb[c + q];
      v[q] = 0.5f * z * (1.f + erff(z * 0.70710678118654752f));
    }
#pragma unroll
    for (int o = 0; o < 96; o++) {
      float4 wv = *(const float4*)(w + (size_t)o * 192 + c);
      acc[o] = fmaf(v[0], wv.x, acc[o]);
      acc[o] = fmaf(v[1], wv.y, acc[o]);
      acc[o] = fmaf(v[2], wv.z, acc[o]);
      acc[o] = fmaf(v[3], wv.w, acc[o]);
    }
  }
  float* op = out + (size_t)n * 96 * HW + pix;
#pragma unroll
  for (int o = 0; o < 96; o++) op[(size_t)o * HW] = acc[o];
}

extern "C" void kernel_launch(void* const* d_in, const int* in_sizes, int n_in,
                              void* d_out, int out_size, void* d_ws, size_t ws_size,
                              hipStream_t stream) {
  const float* x = (const float*)d_in[0];
  const float* cf_w = (const float*)d_in[1];
  const float* gnf_s = (const float*)d_in[2];
  const float* gnf_b = (const float*)d_in[3];
  const float* lb1_w = (const float*)d_in[4];
  const float* lb1_b = (const float*)d_in[5];
  const float* pr1 = (const float*)d_in[6];
  const float* lbd1_w = (const float*)d_in[7];
  const float* lbd1_b = (const float*)d_in[8];
  const float* lb2_w = (const float*)d_in[9];
  const float* lb2_b = (const float*)d_in[10];
  const float* pr2 = (const float*)d_in[11];
  const float* lbd2_w = (const float*)d_in[12];
  const float* lbd2_b = (const float*)d_in[13];
  const float* lb3_w = (const float*)d_in[14];
  const float* lb3_b = (const float*)d_in[15];
  const float* pr3 = (const float*)d_in[16];
  const float* lbd3_w = (const float*)d_in[17];
  const float* lbd3_b = (const float*)d_in[18];
  const float* lb4_w = (const float*)d_in[19];
  const float* lb4_b = (const float*)d_in[20];
  const float* pr4 = (const float*)d_in[21];
  const float* lb5_w = (const float*)d_in[22];
  const float* lb5_b = (const float*)d_in[23];
  const float* gnh_s = (const float*)d_in[24];
  const float* gnh_b = (const float*)d_in[25];
  const float* hb_w = (const float*)d_in[26];
  const float* hb_b = (const float*)d_in[27];
  const float* ff1_w = (const float*)d_in[28];
  const float* ff1_b = (const float*)d_in[29];
  const float* gnff_s = (const float*)d_in[30];
  const float* gnff_b = (const float*)d_in[31];
  const float* ff2_w = (const float*)d_in[32];
  const float* ff2_b = (const float*)d_in[33];

  const size_t SPC = (size_t)8 * 96 * HW;   // 12,582,912 floats
  const size_t YSZ = (size_t)8 * 24 * HW;   // 3,145,728 floats
  float* ws = (float*)d_ws;
  float* buf_low = ws;               // later reused as enh_low
  float* buf_ehigh = ws + SPC;
  float* buf_high = ws + 2 * SPC;
  float* buf_t = ws + 2 * SPC;       // 2*SPC floats; overlaps buf_high (dead by then)
  float* buf_y1 = ws + 4 * SPC;
  float* buf_y2 = buf_y1 + YSZ;
  float* buf_fi = buf_y2 + YSZ;      // 768
  float* buf_filt = buf_fi + 768;    // 6912
  float* buf_hst = buf_filt + 6912;  // 64
  float* buf_ffst = buf_hst + 64;    // 64

  // zero the two stats accumulators (contiguous 128 floats)
  hipMemsetAsync(buf_hst, 0, 128 * sizeof(float), stream);

  k_mean<<<768, 256, 0, stream>>>(x, buf_fi);
  k_filter<<<8, 256, 0, stream>>>(buf_fi, cf_w, gnf_s, gnf_b, buf_filt);
  k_invol<<<dim3(64, 768), 256, 0, stream>>>(x, buf_filt, buf_low, buf_high);

  k_conv1x1<96, 24, true><<<dim3(64, 8), 256, 0, stream>>>(buf_low, lb1_w, lb1_b, pr1, buf_y1);
  k_dw3x3<5><<<dim3(64, 192), 256, 0, stream>>>(buf_y1, lbd1_w, lbd1_b, buf_y2);
  k_conv1x1<24, 24, true><<<dim3(64, 8), 256, 0, stream>>>(buf_y2, lb2_w, lb2_b, pr2, buf_y1);
  k_dw3x3<1><<<dim3(64, 192), 256, 0, stream>>>(buf_y1, lbd2_w, lbd2_b, buf_y2);
  k_conv1x1<24, 24, true><<<dim3(64, 8), 256, 0, stream>>>(buf_y2, lb3_w, lb3_b, pr3, buf_y1);
  k_dw3x3<3><<<dim3(64, 192), 256, 0, stream>>>(buf_y1, lbd3_w, lbd3_b, buf_y2);
  k_conv1x1<24, 24, true><<<dim3(64, 8), 256, 0, stream>>>(buf_y2, lb4_w, lb4_b, pr4, buf_y1);
  k_conv1x1<24, 96, false><<<dim3(64, 8), 256, 0, stream>>>(buf_y1, lb5_w, lb5_b, nullptr,
                                                            buf_low /* enh_low */);

  k_gnhigh_part<<<dim3(32, 8), 256, 0, stream>>>(buf_high, buf_hst);
  k_gnfin<<<1, 32, 0, stream>>>(buf_hst, 1.f / 393216.f);
  k_hbconv<<<dim3(32, 4, 8), 256, 0, stream>>>(buf_high, buf_hst, gnh_s, gnh_b, hb_w, hb_b,
                                               buf_ehigh);

  k_ff1<<<dim3(64, 2, 8), 256, 0, stream>>>(buf_low, buf_ehigh, ff1_w, ff1_b, buf_t, buf_ffst);
  k_gnfin<<<1, 32, 0, stream>>>(buf_ffst, 1.f / 786432.f);
  k_ff2<<<dim3(64, 8), 256, 0, stream>>>(buf_t, buf_ffst, gnff_s, gnff_b, ff2_w, ff2_b,
                                         (float*)d_out);
}

// Round 2
// 960.619 us; speedup vs baseline: 3.2057x; 3.2057x over previous
//
#include <hip/hip_runtime.h>
#include <math.h>

#define HW 16384
#define WIDTH 128

typedef short bf16x8 __attribute__((ext_vector_type(8)));
typedef float f32x4 __attribute__((ext_vector_type(4)));
typedef unsigned short ushort8 __attribute__((ext_vector_type(8)));
typedef unsigned short ushort2v __attribute__((ext_vector_type(2)));

__device__ __forceinline__ float wave_sum(float v) {
#pragma unroll
  for (int o = 32; o > 0; o >>= 1) v += __shfl_down(v, o, 64);
  return v;
}

__device__ __forceinline__ unsigned short f2bf(float f) {
  unsigned u = __float_as_uint(f);
  return (unsigned short)((u + 0x7fffu + ((u >> 16) & 1u)) >> 16);
}

// ---------------- fi = mean over H,W ----------------
__global__ __launch_bounds__(256) void k_mean(const float* __restrict__ x,
                                              float* __restrict__ fi) {
  __shared__ float sm[4];
  int nc = blockIdx.x;  // 0..767
  const float4* p = (const float4*)(x + (size_t)nc * HW);
  float s = 0.f;
  for (int i = threadIdx.x; i < HW / 4; i += 256) {
    float4 v = p[i];
    s += (v.x + v.y) + (v.z + v.w);
  }
  s = wave_sum(s);
  int wid = threadIdx.x >> 6, lane = threadIdx.x & 63;
  if (!lane) sm[wid] = s;
  __syncthreads();
  if (!threadIdx.x) fi[nc] = (sm[0] + sm[1] + sm[2] + sm[3]) * (1.f / 16384.f);
}

// ---------------- dynamic filter: 1x1 conv -> GN(4 groups) -> softmax(9) ----------------
__global__ __launch_bounds__(256) void k_filter(const float* __restrict__ fi,
                                                const float* __restrict__ cf_w,
                                                const float* __restrict__ gnf_s,
                                                const float* __restrict__ gnf_b,
                                                float* __restrict__ filt) {
  int n = blockIdx.x;
  int t = threadIdx.x;
  __shared__ __align__(16) float sfi[96];
  __shared__ float sfw[864];
  __shared__ float gstat[8];
  if (t < 96) sfi[t] = fi[n * 96 + t];
  __syncthreads();
  for (int oc = t; oc < 864; oc += 256) {
    const float4* wr = (const float4*)(cf_w + (size_t)oc * 96);
    const float4* fr = (const float4*)sfi;
    float a = 0.f;
#pragma unroll
    for (int q = 0; q < 24; q++) {
      float4 w4 = wr[q];
      float4 f4 = fr[q];
      a += w4.x * f4.x + w4.y * f4.y + w4.z * f4.z + w4.w * f4.w;
    }
    sfw[oc] = a;
  }
  __syncthreads();
  if (t < 4) {
    float s = 0.f, ss = 0.f;
    for (int i = 0; i < 216; i++) {
      float v = sfw[t * 216 + i];
      s += v;
      ss += v * v;
    }
    float m = s * (1.f / 216.f);
    float var = ss * (1.f / 216.f) - m * m;
    gstat[t * 2] = m;
    gstat[t * 2 + 1] = rsqrtf(var + 1e-5f);
  }
  __syncthreads();
  for (int oc = t; oc < 864; oc += 256) {
    int g = oc / 216;
    sfw[oc] = (sfw[oc] - gstat[g * 2]) * gstat[g * 2 + 1] * gnf_s[oc] + gnf_b[oc];
  }
  __syncthreads();
  if (t < 96) {
    float v[9], mx = -1e30f;
#pragma unroll
    for (int k = 0; k < 9; k++) {
      v[k] = sfw[t * 9 + k];
      mx = fmaxf(mx, v[k]);
    }
    float s = 0.f;
#pragma unroll
    for (int k = 0; k < 9; k++) {
      v[k] = expf(v[k] - mx);
      s += v[k];
    }
    float inv = 1.f / s;
#pragma unroll
    for (int k = 0; k < 9; k++) filt[((size_t)n * 96 + t) * 9 + k] = v[k] * inv;
  }
}

// ---------------- involution (reflect pad, taps {-2,0,2}) + high = x - low ----------------
__global__ __launch_bounds__(256) void k_invol(const float* __restrict__ x,
                                               const float* __restrict__ filt,
                                               float* __restrict__ low,
                                               float* __restrict__ high) {
  int nc = blockIdx.y;
  const float* xp = x + (size_t)nc * HW;
  const float* fp = filt + (size_t)nc * 9;
  float f[9];
#pragma unroll
  for (int k = 0; k < 9; k++) f[k] = fp[k];
  int idx = blockIdx.x * 256 + threadIdx.x;
  int y = idx >> 7, xx = idx & 127;
  int ry[3], rx[3];
#pragma unroll
  for (int d = 0; d < 3; d++) {
    int p = y + 2 * d - 2;
    if (p < 0) p = -p;
    if (p > 127) p = 254 - p;
    ry[d] = p;
    int q = xx + 2 * d - 2;
    if (q < 0) q = -q;
    if (q > 127) q = 254 - q;
    rx[d] = q;
  }
  float acc = 0.f;
#pragma unroll
  for (int i = 0; i < 3; i++)
#pragma unroll
    for (int j = 0; j < 3; j++) acc = fmaf(f[i * 3 + j], xp[ry[i] * WIDTH + rx[j]], acc);
  float xv = xp[idx];
  size_t o = (size_t)nc * HW + idx;
  low[o] = acc;
  high[o] = xv - acc;
}

// ---------------- generic 1x1 conv (+bias, optional PReLU) ----------------
template <int CIN, int COUT, bool PRELU>
__global__ __launch_bounds__(256) void k_conv1x1(const float* __restrict__ in,
                                                 const float* __restrict__ w,
                                                 const float* __restrict__ b,
                                                 const float* __restrict__ pr,
                                                 float* __restrict__ out) {
  int n = blockIdx.y;
  int pix = blockIdx.x * 256 + threadIdx.x;
  const float* ip = in + (size_t)n * CIN * HW + pix;
  float acc[COUT];
#pragma unroll
  for (int o = 0; o < COUT; o++) acc[o] = b[o];
  for (int c = 0; c < CIN; c += 4) {
    float v0 = ip[(size_t)c * HW];
    float v1 = ip[(size_t)(c + 1) * HW];
    float v2 = ip[(size_t)(c + 2) * HW];
    float v3 = ip[(size_t)(c + 3) * HW];
#pragma unroll
    for (int o = 0; o < COUT; o++) {
      float4 wv = *(const float4*)(w + (size_t)o * CIN + c);
      acc[o] = fmaf(v0, wv.x, acc[o]);
      acc[o] = fmaf(v1, wv.y, acc[o]);
      acc[o] = fmaf(v2, wv.z, acc[o]);
      acc[o] = fmaf(v3, wv.w, acc[o]);
    }
  }
  float a = PRELU ? pr[0] : 0.f;
  float* op = out + (size_t)n * COUT * HW + pix;
#pragma unroll
  for (int o = 0; o < COUT; o++) {
    float v = acc[o];
    if (PRELU) v = v >= 0.f ? v : a * v;
    op[(size_t)o * HW] = v;
  }
}

// ---------------- depthwise 3x3, zero pad = dilation ----------------
template <int DILA>
__global__ __launch_bounds__(256) void k_dw3x3(const float* __restrict__ in,
                                               const float* __restrict__ w,
                                               const float* __restrict__ b,
                                               float* __restrict__ out) {
  int ncz = blockIdx.y;  // n*24+c
  int c = ncz % 24;
  float wt[9];
#pragma unroll
  for (int k = 0; k < 9; k++) wt[k] = w[c * 9 + k];
  float acc = b[c];
  int pix = blockIdx.x * 256 + threadIdx.x;
  int y = pix >> 7, xx = pix & 127;
  const float* ip = in + (size_t)ncz * HW;
#pragma unroll
  for (int i = 0; i < 3; i++) {
    int yy = y + DILA * (i - 1);
    if (yy < 0 || yy >= 128) continue;
#pragma unroll
    for (int j = 0; j < 3; j++) {
      int xj = xx + DILA * (j - 1);
      if (xj < 0 || xj >= 128) continue;
      acc = fmaf(wt[i * 3 + j], ip[yy * WIDTH + xj], acc);
    }
  }
  out[(size_t)ncz * HW + pix] = acc;
}

// ---------------- GN stats for high: partial sums (atomic) ----------------
__global__ __launch_bounds__(256) void k_gnhigh_part(const float* __restrict__ h,
                                                     float* __restrict__ stats) {
  int ng = blockIdx.x;  // n*4+g, region = 24*HW contiguous
  const float4* p = (const float4*)(h + (size_t)ng * 393216 + (size_t)blockIdx.y * 49152);
  float s = 0.f, ss = 0.f;
  for (int i = threadIdx.x; i < 12288; i += 256) {
    float4 v = p[i];
    s += (v.x + v.y) + (v.z + v.w);
    ss += (v.x * v.x + v.y * v.y) + (v.z * v.z + v.w * v.w);
  }
  s = wave_sum(s);
  ss = wave_sum(ss);
  __shared__ float sm[8];
  int wid = threadIdx.x >> 6, lane = threadIdx.x & 63;
  if (!lane) {
    sm[wid] = s;
    sm[4 + wid] = ss;
  }
  __syncthreads();
  if (!threadIdx.x) {
    atomicAdd(&stats[ng * 2], sm[0] + sm[1] + sm[2] + sm[3]);
    atomicAdd(&stats[ng * 2 + 1], sm[4] + sm[5] + sm[6] + sm[7]);
  }
}

// ---------------- finalize GN stats: sum,sumsq -> mean,invstd ----------------
__global__ void k_gnfin(float* stats, float inv_cnt) {
  int i = threadIdx.x;  // 32 = n*groups
  float s = stats[i * 2], ss = stats[i * 2 + 1];
  float m = s * inv_cnt;
  float var = ss * inv_cnt - m * m;
  stats[i * 2] = m;
  stats[i * 2 + 1] = rsqrtf(var + 1e-5f);
}

// ---------------- prep: GN+leaky on high -> bf16, transpose to [n][y][x][cin] ----------------
__global__ __launch_bounds__(256) void k_prep_hn(const float* __restrict__ high,
                                                 const float* __restrict__ hstats,
                                                 const float* __restrict__ gs,
                                                 const float* __restrict__ gb,
                                                 unsigned short* __restrict__ hn) {
  __shared__ unsigned short sm[64 * 104];
  int n = blockIdx.y;
  int px0 = blockIdx.x * 64;
  int t = threadIdx.x;
  int px = t & 63, cg = t >> 6;  // cg 0..3
  float hm[4], hi[4];
#pragma unroll
  for (int g = 0; g < 4; g++) {
    hm[g] = hstats[(n * 4 + g) * 2];
    hi[g] = hstats[(n * 4 + g) * 2 + 1];
  }
#pragma unroll
  for (int c0 = 0; c0 < 96; c0 += 8) {
    int c = c0 + cg * 2;
    int g = c / 24;
    float v0 = high[((size_t)(n * 96 + c)) * HW + px0 + px];
    float v1 = high[((size_t)(n * 96 + c + 1)) * HW + px0 + px];
    float h0 = (v0 - hm[g]) * hi[g] * gs[c] + gb[c];
    float h1 = (v1 - hm[g]) * hi[g] * gs[c + 1] + gb[c + 1];
    h0 = h0 >= 0.f ? h0 : 0.01f * h0;
    h1 = h1 >= 0.f ? h1 : 0.01f * h1;
    ushort2v p;
    p.x = f2bf(h0);
    p.y = f2bf(h1);
    *(ushort2v*)&sm[px * 104 + c] = p;
  }
  __syncthreads();
#pragma unroll
  for (int k = 0; k < 3; k++) {
    int idx = t + k * 256;  // 768 chunks
    int p = idx / 12, c8 = idx % 12;
    ushort8 v = *(ushort8*)&sm[p * 104 + c8 * 8];
    *(ushort8*)&hn[((size_t)n * HW + px0 + p) * 96 + c8 * 8] = v;
  }
}

// ---------------- prep: hb weights fp32 [oc][cin][3][3] -> bf16 [tap][oc][cin] ----------------
__global__ __launch_bounds__(256) void k_prep_w(const float* __restrict__ w,
                                                unsigned short* __restrict__ wbf) {
  int i = blockIdx.x * 256 + threadIdx.x;  // 82944
  int tap = i / 9216;
  int r = i - tap * 9216;
  int oc = r / 96, cin = r - oc * 96;
  wbf[i] = f2bf(w[(size_t)(oc * 96 + cin) * 9 + tap]);
}

// ---------------- hb 3x3 conv 96->96 as implicit-GEMM MFMA + bias + residual ----------------
__global__ __launch_bounds__(256) void k_hbconv_mfma(const unsigned short* __restrict__ hn,
                                                     const unsigned short* __restrict__ wbf,
                                                     const float* __restrict__ bias,
                                                     const float* __restrict__ high,
                                                     float* __restrict__ out) {
  // grid (4 xt, 32 yt, 8 n); block 256 = 4 waves. Tile: 96 oc x (4y x 32x) px.
  __shared__ __align__(16) unsigned short stile[6 * 34 * 104];  // [ly][lx][cin pad 104]
  int t = threadIdx.x;
  int n = blockIdx.z;
  int x0 = blockIdx.x * 32, y0 = blockIdx.y * 4;
  // stage halo tile: rows y0-1..y0+4, cols x0-1..x0+32
  for (int idx = t; idx < 2448; idx += 256) {
    int p = idx / 12, c8 = idx % 12;
    int ly = p / 34, lx = p - ly * 34;
    int gy = y0 + ly - 1, gx = x0 + lx - 1;
    ushort8 v = (ushort8)0;
    if ((unsigned)gy < 128u && (unsigned)gx < 128u)
      v = *(const ushort8*)&hn[((size_t)n * HW + gy * 128 + gx) * 96 + c8 * 8];
    *(ushort8*)&stile[(ly * 34 + lx) * 104 + c8 * 8] = v;
  }
  __syncthreads();
  int wv = t >> 6;  // wave = y row of tile
  int lane = t & 63;
  int l15 = lane & 15, l4 = lane >> 4;
  f32x4 acc[6][2];
#pragma unroll
  for (int mf = 0; mf < 6; mf++)
#pragma unroll
    for (int nf = 0; nf < 2; nf++) acc[mf][nf] = (f32x4)0.f;
#pragma unroll 1
  for (int tap = 0; tap < 9; tap++) {
    int ky = tap / 3, kx = tap - ky * 3;
    const unsigned short* wt = wbf + (size_t)tap * 9216;
#pragma unroll
    for (int kk = 0; kk < 3; kk++) {
      bf16x8 a[6], b[2];
#pragma unroll
      for (int mf = 0; mf < 6; mf++)
        a[mf] = *(const bf16x8*)&wt[(mf * 16 + l15) * 96 + kk * 32 + l4 * 8];
#pragma unroll
      for (int nf = 0; nf < 2; nf++) {
        int p = (wv + ky) * 34 + (nf * 16 + l15 + kx);
        b[nf] = *(const bf16x8*)&stile[p * 104 + kk * 32 + l4 * 8];
      }
#pragma unroll
      for (int mf = 0; mf < 6; mf++)
#pragma unroll
        for (int nf = 0; nf < 2; nf++)
          acc[mf][nf] = __builtin_amdgcn_mfma_f32_16x16x32_bf16(a[mf], b[nf], acc[mf][nf], 0, 0, 0);
    }
  }
  int gy = y0 + wv;
#pragma unroll
  for (int mf = 0; mf < 6; mf++) {
#pragma unroll
    for (int r = 0; r < 4; r++) {
      int oc = mf * 16 + l4 * 4 + r;
      float bv = bias[oc];
#pragma unroll
      for (int nf = 0; nf < 2; nf++) {
        int gx = x0 + nf * 16 + l15;
        size_t o = ((size_t)(n * 96 + oc)) * HW + gy * 128 + gx;
        out[o] = acc[mf][nf][r] + bv + high[o];
      }
    }
  }
}

// ---------------- ff1: 1x1 192->192, quarter of oc per block (= one GN group) ----------------
__global__ __launch_bounds__(256) void k_ff1q(const float* __restrict__ elow,
                                              const float* __restrict__ ehigh,
                                              const float* __restrict__ w,
                                              const float* __restrict__ bias,
                                              float* __restrict__ t,
                                              float* __restrict__ ffstats) {
  int n = blockIdx.z, q = blockIdx.y;
  int pix = blockIdx.x * 256 + threadIdx.x;
  float acc[48];
#pragma unroll
  for (int o = 0; o < 48; o++) acc[o] = 0.f;
  const float* ilow = elow + (size_t)n * 96 * HW + pix;
  const float* ihigh = ehigh + (size_t)n * 96 * HW + pix;
  const float* wb = w + (size_t)q * 48 * 192;
  for (int c = 0; c < 96; c += 4) {
    float v0 = ilow[(size_t)c * HW], v1 = ilow[(size_t)(c + 1) * HW];
    float v2 = ilow[(size_t)(c + 2) * HW], v3 = ilow[(size_t)(c + 3) * HW];
#pragma unroll
    for (int o = 0; o < 48; o++) {
      float4 wv = *(const float4*)(wb + (size_t)o * 192 + c);
      acc[o] = fmaf(v0, wv.x, acc[o]);
      acc[o] = fmaf(v1, wv.y, acc[o]);
      acc[o] = fmaf(v2, wv.z, acc[o]);
      acc[o] = fmaf(v3, wv.w, acc[o]);
    }
  }
  for (int c = 0; c < 96; c += 4) {
    float v0 = ihigh[(size_t)c * HW], v1 = ihigh[(size_t)(c + 1) * HW];
    float v2 = ihigh[(size_t)(c + 2) * HW], v3 = ihigh[(size_t)(c + 3) * HW];
#pragma unroll
    for (int o = 0; o < 48; o++) {
      float4 wv = *(const float4*)(wb + (size_t)o * 192 + 96 + c);
      acc[o] = fmaf(v0, wv.x, acc[o]);
      acc[o] = fmaf(v1, wv.y, acc[o]);
      acc[o] = fmaf(v2, wv.z, acc[o]);
      acc[o] = fmaf(v3, wv.w, acc[o]);
    }
  }
  float s = 0.f, ss = 0.f;
  float* tp = t + ((size_t)n * 192 + q * 48) * HW + pix;
#pragma unroll
  for (int o = 0; o < 48; o++) {
    float v = acc[o] + bias[q * 48 + o];
    tp[(size_t)o * HW] = v;
    s += v;
    ss += v * v;
  }
  s = wave_sum(s);
  ss = wave_sum(ss);
  __shared__ float sred[4][2];
  int wid = threadIdx.x >> 6, lane = threadIdx.x & 63;
  if (!lane) {
    sred[wid][0] = s;
    sred[wid][1] = ss;
  }
  __syncthreads();
  if (threadIdx.x < 2) {
    int v = threadIdx.x;
    float tot = sred[0][v] + sred[1][v] + sred[2][v] + sred[3][v];
    atomicAdd(&ffstats[(n * 4 + q) * 2 + v], tot);
  }
}

// ---------------- ff2: GN->gelu(exact) fused, 1x1 192->96, half of oc per block ----------------
__global__ __launch_bounds__(256) void k_ff2h(const float* __restrict__ t,
                                              const float* __restrict__ ffstats,
                                              const float* __restrict__ gs,
                                              const float* __restrict__ gb,
                                              const float* __restrict__ w,
                                              const float* __restrict__ bias,
                                              float* __restrict__ out) {
  int n = blockIdx.z, hf = blockIdx.y;
  int pix = blockIdx.x * 256 + threadIdx.x;
  float acc[48];
#pragma unroll
  for (int o = 0; o < 48; o++) acc[o] = bias[hf * 48 + o];
  const float* tp = t + (size_t)n * 192 * HW + pix;
  float fm[4], fv[4];
#pragma unroll
  for (int g = 0; g < 4; g++) {
    fm[g] = ffstats[(n * 4 + g) * 2];
    fv[g] = ffstats[(n * 4 + g) * 2 + 1];
  }
  const float* wb = w + (size_t)hf * 48 * 192;
  for (int c = 0; c < 192; c += 4) {
    int g = c / 48;
    float v[4];
#pragma unroll
    for (int q = 0; q < 4; q++) {
      float raw = tp[(size_t)(c + q) * HW];
      float z = (raw - fm[g]) * fv[g] * gs[c + q] + gb[c + q];
      v[q] = 0.5f * z * (1.f + erff(z * 0.70710678118654752f));
    }
#pragma unroll
    for (int o = 0; o < 48; o++) {
      float4 wv = *(const float4*)(wb + (size_t)o * 192 + c);
      acc[o] = fmaf(v[0], wv.x, acc[o]);
      acc[o] = fmaf(v[1], wv.y, acc[o]);
      acc[o] = fmaf(v[2], wv.z, acc[o]);
      acc[o] = fmaf(v[3], wv.w, acc[o]);
    }
  }
  float* op = out + ((size_t)n * 96 + hf * 48) * HW + pix;
#pragma unroll
  for (int o = 0; o < 48; o++) op[(size_t)o * HW] = acc[o];
}

extern "C" void kernel_launch(void* const* d_in, const int* in_sizes, int n_in,
                              void* d_out, int out_size, void* d_ws, size_t ws_size,
                              hipStream_t stream) {
  const float* x = (const float*)d_in[0];
  const float* cf_w = (const float*)d_in[1];
  const float* gnf_s = (const float*)d_in[2];
  const float* gnf_b = (const float*)d_in[3];
  const float* lb1_w = (const float*)d_in[4];
  const float* lb1_b = (const float*)d_in[5];
  const float* pr1 = (const float*)d_in[6];
  const float* lbd1_w = (const float*)d_in[7];
  const float* lbd1_b = (const float*)d_in[8];
  const float* lb2_w = (const float*)d_in[9];
  const float* lb2_b = (const float*)d_in[10];
  const float* pr2 = (const float*)d_in[11];
  const float* lbd2_w = (const float*)d_in[12];
  const float* lbd2_b = (const float*)d_in[13];
  const float* lb3_w = (const float*)d_in[14];
  const float* lb3_b = (const float*)d_in[15];
  const float* pr3 = (const float*)d_in[16];
  const float* lbd3_w = (const float*)d_in[17];
  const float* lbd3_b = (const float*)d_in[18];
  const float* lb4_w = (const float*)d_in[19];
  const float* lb4_b = (const float*)d_in[20];
  const float* pr4 = (const float*)d_in[21];
  const float* lb5_w = (const float*)d_in[22];
  const float* lb5_b = (const float*)d_in[23];
  const float* gnh_s = (const float*)d_in[24];
  const float* gnh_b = (const float*)d_in[25];
  const float* hb_w = (const float*)d_in[26];
  const float* hb_b = (const float*)d_in[27];
  const float* ff1_w = (const float*)d_in[28];
  const float* ff1_b = (const float*)d_in[29];
  const float* gnff_s = (const float*)d_in[30];
  const float* gnff_b = (const float*)d_in[31];
  const float* ff2_w = (const float*)d_in[32];
  const float* ff2_b = (const float*)d_in[33];

  const size_t SPC = (size_t)8 * 96 * HW;  // 12,582,912 floats
  const size_t YSZ = (size_t)8 * 24 * HW;
  float* ws = (float*)d_ws;
  float* buf_low = ws;           // later reused as enh_low
  float* buf_ehigh = ws + SPC;
  float* buf_high = ws + 2 * SPC;
  float* buf_t = ws + 2 * SPC;   // overlaps buf_high (dead by ff1 time)
  // hn/wbf live in 3*SPC..4*SPC (t's upper half; free until ff1)
  unsigned short* buf_hn = (unsigned short*)(ws + 3 * SPC);
  unsigned short* buf_wbf = (unsigned short*)(ws + 3 * SPC + 6400000);
  float* buf_y1 = ws + 4 * SPC;
  float* buf_y2 = buf_y1 + YSZ;
  float* buf_fi = buf_y2 + YSZ;      // 768
  float* buf_filt = buf_fi + 768;    // 6912
  float* buf_hst = buf_filt + 6912;  // 64
  float* buf_ffst = buf_hst + 64;    // 64

  hipMemsetAsync(buf_hst, 0, 128 * sizeof(float), stream);

  k_mean<<<768, 256, 0, stream>>>(x, buf_fi);
  k_filter<<<8, 256, 0, stream>>>(buf_fi, cf_w, gnf_s, gnf_b, buf_filt);
  k_invol<<<dim3(64, 768), 256, 0, stream>>>(x, buf_filt, buf_low, buf_high);

  k_conv1x1<96, 24, true><<<dim3(64, 8), 256, 0, stream>>>(buf_low, lb1_w, lb1_b, pr1, buf_y1);
  k_dw3x3<5><<<dim3(64, 192), 256, 0, stream>>>(buf_y1, lbd1_w, lbd1_b, buf_y2);
  k_conv1x1<24, 24, true><<<dim3(64, 8), 256, 0, stream>>>(buf_y2, lb2_w, lb2_b, pr2, buf_y1);
  k_dw3x3<1><<<dim3(64, 192), 256, 0, stream>>>(buf_y1, lbd2_w, lbd2_b, buf_y2);
  k_conv1x1<24, 24, true><<<dim3(64, 8), 256, 0, stream>>>(buf_y2, lb3_w, lb3_b, pr3, buf_y1);
  k_dw3x3<3><<<dim3(64, 192), 256, 0, stream>>>(buf_y1, lbd3_w, lbd3_b, buf_y2);
  k_conv1x1<24, 24, true><<<dim3(64, 8), 256, 0, stream>>>(buf_y2, lb4_w, lb4_b, pr4, buf_y1);
  k_conv1x1<24, 96, false><<<dim3(64, 8), 256, 0, stream>>>(buf_y1, lb5_w, lb5_b, nullptr,
                                                            buf_low /* enh_low */);

  k_gnhigh_part<<<dim3(32, 8), 256, 0, stream>>>(buf_high, buf_hst);
  k_gnfin<<<1, 32, 0, stream>>>(buf_hst, 1.f / 393216.f);
  k_prep_w<<<324, 256, 0, stream>>>(hb_w, buf_wbf);
  k_prep_hn<<<dim3(256, 8), 256, 0, stream>>>(buf_high, buf_hst, gnh_s, gnh_b, buf_hn);
  k_hbconv_mfma<<<dim3(4, 32, 8), 256, 0, stream>>>(buf_hn, buf_wbf, hb_b, buf_high, buf_ehigh);

  k_ff1q<<<dim3(64, 4, 8), 256, 0, stream>>>(buf_low, buf_ehigh, ff1_w, ff1_b, buf_t, buf_ffst);
  k_gnfin<<<1, 32, 0, stream>>>(buf_ffst, 1.f / 786432.f);
  k_ff2h<<<dim3(64, 2, 8), 256, 0, stream>>>(buf_t, buf_ffst, gnff_s, gnff_b, ff2_w, ff2_b,
                                             (float*)d_out);
}

// Round 5
// 707.471 us; speedup vs baseline: 4.3528x; 1.3578x over previous
//
#include <hip/hip_runtime.h>
#include <math.h>

#define HW 16384
#define WIDTH 128

typedef short bf16x8 __attribute__((ext_vector_type(8)));
typedef float f32x4 __attribute__((ext_vector_type(4)));
typedef unsigned short ushort8 __attribute__((ext_vector_type(8)));
typedef unsigned short ushort4v __attribute__((ext_vector_type(4)));
typedef unsigned short ushort2v __attribute__((ext_vector_type(2)));

__device__ __forceinline__ float wave_sum(float v) {
#pragma unroll
  for (int o = 32; o > 0; o >>= 1) v += __shfl_down(v, o, 64);
  return v;
}

__device__ __forceinline__ unsigned short f2bf(float f) {
  unsigned u = __float_as_uint(f);
  return (unsigned short)((u + 0x7fffu + ((u >> 16) & 1u)) >> 16);
}

__device__ __forceinline__ float bf2f(unsigned short s) {
  return __uint_as_float((unsigned)s << 16);
}

// ---------------- fi = mean over H,W ----------------
__global__ __launch_bounds__(256) void k_mean(const float* __restrict__ x,
                                              float* __restrict__ fi) {
  __shared__ float sm[4];
  int nc = blockIdx.x;  // 0..767
  const float4* p = (const float4*)(x + (size_t)nc * HW);
  float s = 0.f;
  for (int i = threadIdx.x; i < HW / 4; i += 256) {
    float4 v = p[i];
    s += (v.x + v.y) + (v.z + v.w);
  }
  s = wave_sum(s);
  int wid = threadIdx.x >> 6, lane = threadIdx.x & 63;
  if (!lane) sm[wid] = s;
  __syncthreads();
  if (!threadIdx.x) fi[nc] = (sm[0] + sm[1] + sm[2] + sm[3]) * (1.f / 16384.f);
}

// ---------------- dynamic filter: 1x1 conv -> GN(4 groups) -> softmax(9) ----------------
__global__ __launch_bounds__(256) void k_filter(const float* __restrict__ fi,
                                                const float* __restrict__ cf_w,
                                                const float* __restrict__ gnf_s,
                                                const float* __restrict__ gnf_b,
                                                float* __restrict__ filt) {
  int n = blockIdx.x;
  int t = threadIdx.x;
  __shared__ __align__(16) float sfi[96];
  __shared__ float sfw[864];
  __shared__ float gstat[8];
  if (t < 96) sfi[t] = fi[n * 96 + t];
  __syncthreads();
  for (int oc = t; oc < 864; oc += 256) {
    const float4* wr = (const float4*)(cf_w + (size_t)oc * 96);
    const float4* fr = (const float4*)sfi;
    float a = 0.f;
#pragma unroll
    for (int q = 0; q < 24; q++) {
      float4 w4 = wr[q];
      float4 f4 = fr[q];
      a += w4.x * f4.x + w4.y * f4.y + w4.z * f4.z + w4.w * f4.w;
    }
    sfw[oc] = a;
  }
  __syncthreads();
  if (t < 4) {
    float s = 0.f, ss = 0.f;
    for (int i = 0; i < 216; i++) {
      float v = sfw[t * 216 + i];
      s += v;
      ss += v * v;
    }
    float m = s * (1.f / 216.f);
    float var = ss * (1.f / 216.f) - m * m;
    gstat[t * 2] = m;
    gstat[t * 2 + 1] = rsqrtf(var + 1e-5f);
  }
  __syncthreads();
  for (int oc = t; oc < 864; oc += 256) {
    int g = oc / 216;
    sfw[oc] = (sfw[oc] - gstat[g * 2]) * gstat[g * 2 + 1] * gnf_s[oc] + gnf_b[oc];
  }
  __syncthreads();
  if (t < 96) {
    float v[9], mx = -1e30f;
#pragma unroll
    for (int k = 0; k < 9; k++) {
      v[k] = sfw[t * 9 + k];
      mx = fmaxf(mx, v[k]);
    }
    float s = 0.f;
#pragma unroll
    for (int k = 0; k < 9; k++) {
      v[k] = expf(v[k] - mx);
      s += v[k];
    }
    float inv = 1.f / s;
#pragma unroll
    for (int k = 0; k < 9; k++) filt[((size_t)n * 96 + t) * 9 + k] = v[k] * inv;
  }
}

// ---------------- involution (reflect pad, taps {-2,0,2}) + high = x - low ----------------
__global__ __launch_bounds__(256) void k_invol(const float* __restrict__ x,
                                               const float* __restrict__ filt,
                                               float* __restrict__ low,
                                               float* __restrict__ high) {
  int nc = blockIdx.y;
  const float* xp = x + (size_t)nc * HW;
  const float* fp = filt + (size_t)nc * 9;
  float f[9];
#pragma unroll
  for (int k = 0; k < 9; k++) f[k] = fp[k];
  int idx = blockIdx.x * 256 + threadIdx.x;
  int y = idx >> 7, xx = idx & 127;
  int ry[3], rx[3];
#pragma unroll
  for (int d = 0; d < 3; d++) {
    int p = y + 2 * d - 2;
    if (p < 0) p = -p;
    if (p > 127) p = 254 - p;
    ry[d] = p;
    int q = xx + 2 * d - 2;
    if (q < 0) q = -q;
    if (q > 127) q = 254 - q;
    rx[d] = q;
  }
  float acc = 0.f;
#pragma unroll
  for (int i = 0; i < 3; i++)
#pragma unroll
    for (int j = 0; j < 3; j++) acc = fmaf(f[i * 3 + j], xp[ry[i] * WIDTH + rx[j]], acc);
  float xv = xp[idx];
  size_t o = (size_t)nc * HW + idx;
  low[o] = acc;
  high[o] = xv - acc;
}

// ---------------- generic 1x1 conv (+bias, optional PReLU) ----------------
template <int CIN, int COUT, bool PRELU>
__global__ __launch_bounds__(256) void k_conv1x1(const float* __restrict__ in,
                                                 const float* __restrict__ w,
                                                 const float* __restrict__ b,
                                                 const float* __restrict__ pr,
                                                 float* __restrict__ out) {
  int n = blockIdx.y;
  int pix = blockIdx.x * 256 + threadIdx.x;
  const float* ip = in + (size_t)n * CIN * HW + pix;
  float acc[COUT];
#pragma unroll
  for (int o = 0; o < COUT; o++) acc[o] = b[o];
  for (int c = 0; c < CIN; c += 4) {
    float v0 = ip[(size_t)c * HW];
    float v1 = ip[(size_t)(c + 1) * HW];
    float v2 = ip[(size_t)(c + 2) * HW];
    float v3 = ip[(size_t)(c + 3) * HW];
#pragma unroll
    for (int o = 0; o < COUT; o++) {
      float4 wv = *(const float4*)(w + (size_t)o * CIN + c);
      acc[o] = fmaf(v0, wv.x, acc[o]);
      acc[o] = fmaf(v1, wv.y, acc[o]);
      acc[o] = fmaf(v2, wv.z, acc[o]);
      acc[o] = fmaf(v3, wv.w, acc[o]);
    }
  }
  float a = PRELU ? pr[0] : 0.f;
  float* op = out + (size_t)n * COUT * HW + pix;
#pragma unroll
  for (int o = 0; o < COUT; o++) {
    float v = acc[o];
    if (PRELU) v = v >= 0.f ? v : a * v;
    op[(size_t)o * HW] = v;
  }
}

// ---------------- lb5: 1x1 24->96, writes bf16 NHWC ----------------
__global__ __launch_bounds__(256) void k_lb5(const float* __restrict__ in,
                                             const float* __restrict__ w,
                                             const float* __restrict__ b,
                                             unsigned short* __restrict__ out) {
  int n = blockIdx.y;
  int pix = blockIdx.x * 256 + threadIdx.x;
  const float* ip = in + (size_t)n * 24 * HW + pix;
  float acc[96];
#pragma unroll
  for (int o = 0; o < 96; o++) acc[o] = b[o];
  for (int c = 0; c < 24; c += 4) {
    float v0 = ip[(size_t)c * HW];
    float v1 = ip[(size_t)(c + 1) * HW];
    float v2 = ip[(size_t)(c + 2) * HW];
    float v3 = ip[(size_t)(c + 3) * HW];
#pragma unroll
    for (int o = 0; o < 96; o++) {
      float4 wv = *(const float4*)(w + (size_t)o * 24 + c);
      acc[o] = fmaf(v0, wv.x, acc[o]);
      acc[o] = fmaf(v1, wv.y, acc[o]);
      acc[o] = fmaf(v2, wv.z, acc[o]);
      acc[o] = fmaf(v3, wv.w, acc[o]);
    }
  }
  unsigned short* op = out + ((size_t)n * HW + pix) * 96;
#pragma unroll
  for (int c8 = 0; c8 < 12; c8++) {
    ushort8 pk;
#pragma unroll
    for (int j = 0; j < 8; j++) pk[j] = f2bf(acc[c8 * 8 + j]);
    *(ushort8*)&op[c8 * 8] = pk;
  }
}

// ---------------- depthwise 3x3, zero pad = dilation ----------------
template <int DILA>
__global__ __launch_bounds__(256) void k_dw3x3(const float* __restrict__ in,
                                               const float* __restrict__ w,
                                               const float* __restrict__ b,
                                               float* __restrict__ out) {
  int ncz = blockIdx.y;  // n*24+c
  int c = ncz % 24;
  float wt[9];
#pragma unroll
  for (int k = 0; k < 9; k++) wt[k] = w[c * 9 + k];
  float acc = b[c];
  int pix = blockIdx.x * 256 + threadIdx.x;
  int y = pix >> 7, xx = pix & 127;
  const float* ip = in + (size_t)ncz * HW;
#pragma unroll
  for (int i = 0; i < 3; i++) {
    int yy = y + DILA * (i - 1);
    if (yy < 0 || yy >= 128) continue;
#pragma unroll
    for (int j = 0; j < 3; j++) {
      int xj = xx + DILA * (j - 1);
      if (xj < 0 || xj >= 128) continue;
      acc = fmaf(wt[i * 3 + j], ip[yy * WIDTH + xj], acc);
    }
  }
  out[(size_t)ncz * HW + pix] = acc;
}

// ---------------- GN stats for high: partial sums (atomic) ----------------
__global__ __launch_bounds__(256) void k_gnhigh_part(const float* __restrict__ h,
                                                     float* __restrict__ stats) {
  int ng = blockIdx.x;  // n*4+g, region = 24*HW contiguous
  const float4* p = (const float4*)(h + (size_t)ng * 393216 + (size_t)blockIdx.y * 49152);
  float s = 0.f, ss = 0.f;
  for (int i = threadIdx.x; i < 12288; i += 256) {
    float4 v = p[i];
    s += (v.x + v.y) + (v.z + v.w);
    ss += (v.x * v.x + v.y * v.y) + (v.z * v.z + v.w * v.w);
  }
  s = wave_sum(s);
  ss = wave_sum(ss);
  __shared__ float sm[8];
  int wid = threadIdx.x >> 6, lane = threadIdx.x & 63;
  if (!lane) {
    sm[wid] = s;
    sm[4 + wid] = ss;
  }
  __syncthreads();
  if (!threadIdx.x) {
    atomicAdd(&stats[ng * 2], sm[0] + sm[1] + sm[2] + sm[3]);
    atomicAdd(&stats[ng * 2 + 1], sm[4] + sm[5] + sm[6] + sm[7]);
  }
}

// ---------------- finalize GN stats: sum,sumsq -> mean,invstd ----------------
__global__ void k_gnfin(float* stats, float inv_cnt) {
  int i = threadIdx.x;  // 32 = n*groups
  float s = stats[i * 2], ss = stats[i * 2 + 1];
  float m = s * inv_cnt;
  float var = ss * inv_cnt - m * m;
  stats[i * 2] = m;
  stats[i * 2 + 1] = rsqrtf(var + 1e-5f);
}

// ---------------- prep: GN+leaky on high -> bf16, transpose to [n][y][x][cin] ----------------
__global__ __launch_bounds__(256) void k_prep_hn(const float* __restrict__ high,
                                                 const float* __restrict__ hstats,
                                                 const float* __restrict__ gs,
                                                 const float* __restrict__ gb,
                                                 unsigned short* __restrict__ hn) {
  __shared__ unsigned short sm[64 * 104];
  int n = blockIdx.y;
  int px0 = blockIdx.x * 64;
  int t = threadIdx.x;
  int px = t & 63, cg = t >> 6;  // cg 0..3
  float hm[4], hi[4];
#pragma unroll
  for (int g = 0; g < 4; g++) {
    hm[g] = hstats[(n * 4 + g) * 2];
    hi[g] = hstats[(n * 4 + g) * 2 + 1];
  }
#pragma unroll
  for (int c0 = 0; c0 < 96; c0 += 8) {
    int c = c0 + cg * 2;
    int g = c / 24;
    float v0 = high[((size_t)(n * 96 + c)) * HW + px0 + px];
    float v1 = high[((size_t)(n * 96 + c + 1)) * HW + px0 + px];
    float h0 = (v0 - hm[g]) * hi[g] * gs[c] + gb[c];
    float h1 = (v1 - hm[g]) * hi[g] * gs[c + 1] + gb[c + 1];
    h0 = h0 >= 0.f ? h0 : 0.01f * h0;
    h1 = h1 >= 0.f ? h1 : 0.01f * h1;
    ushort2v p;
    p.x = f2bf(h0);
    p.y = f2bf(h1);
    *(ushort2v*)&sm[px * 104 + c] = p;
  }
  __syncthreads();
#pragma unroll
  for (int k = 0; k < 3; k++) {
    int idx = t + k * 256;  // 768 chunks
    int p = idx / 12, c8 = idx % 12;
    ushort8 v = *(ushort8*)&sm[p * 104 + c8 * 8];
    *(ushort8*)&hn[((size_t)n * HW + px0 + p) * 96 + c8 * 8] = v;
  }
}

// ---------------- prep: hb weights fp32 [oc][cin][3][3] -> bf16 [tap][oc][cin] ----------------
__global__ __launch_bounds__(256) void k_prep_w(const float* __restrict__ w,
                                                unsigned short* __restrict__ wbf) {
  int i = blockIdx.x * 256 + threadIdx.x;  // 82944
  int tap = i / 9216;
  int r = i - tap * 9216;
  int oc = r / 96, cin = r - oc * 96;
  wbf[i] = f2bf(w[(size_t)(oc * 96 + cin) * 9 + tap]);
}

// ---------------- prep: ff1/ff2 weights -> bf16 (same [oc][cin] layout) ----------------
__global__ __launch_bounds__(256) void k_prep_ffw(const float* __restrict__ w1,
                                                  const float* __restrict__ w2,
                                                  unsigned short* __restrict__ o1,
                                                  unsigned short* __restrict__ o2) {
  int i = blockIdx.x * 256 + threadIdx.x;  // 55296
  if (i < 36864)
    o1[i] = f2bf(w1[i]);
  else
    o2[i - 36864] = f2bf(w2[i - 36864]);
}

// ---------------- hb 3x3 conv 96->96 implicit-GEMM MFMA + bias + residual -> bf16 NHWC ----
__global__ __launch_bounds__(256) void k_hbconv_mfma(const unsigned short* __restrict__ hn,
                                                     const unsigned short* __restrict__ wbf,
                                                     const float* __restrict__ bias,
                                                     const float* __restrict__ high,
                                                     unsigned short* __restrict__ ehigh) {
  // grid (4 xt, 32 yt, 8 n); block 256 = 4 waves. Tile: 96 oc x (4y x 32x) px.
  __shared__ __align__(16) unsigned short stile[6 * 34 * 104];  // also reused as sT[128][104]
  int t = threadIdx.x;
  int n = blockIdx.z;
  int x0 = blockIdx.x * 32, y0 = blockIdx.y * 4;
  for (int idx = t; idx < 2448; idx += 256) {
    int p = idx / 12, c8 = idx % 12;
    int ly = p / 34, lx = p - ly * 34;
    int gy = y0 + ly - 1, gx = x0 + lx - 1;
    ushort8 v = (ushort8)0;
    if ((unsigned)gy < 128u && (unsigned)gx < 128u)
      v = *(const ushort8*)&hn[((size_t)n * HW + gy * 128 + gx) * 96 + c8 * 8];
    *(ushort8*)&stile[(ly * 34 + lx) * 104 + c8 * 8] = v;
  }
  __syncthreads();
  int wv = t >> 6;  // wave = y row of tile
  int lane = t & 63;
  int l15 = lane & 15, l4 = lane >> 4;
  f32x4 acc[6][2];
#pragma unroll
  for (int mf = 0; mf < 6; mf++)
#pragma unroll
    for (int nf = 0; nf < 2; nf++) acc[mf][nf] = (f32x4)0.f;
#pragma unroll 1
  for (int tap = 0; tap < 9; tap++) {
    int ky = tap / 3, kx = tap - ky * 3;
    const unsigned short* wt = wbf + (size_t)tap * 9216;
#pragma unroll
    for (int kk = 0; kk < 3; kk++) {
      bf16x8 a[6], b[2];
#pragma unroll
      for (int mf = 0; mf < 6; mf++)
        a[mf] = *(const bf16x8*)&wt[(mf * 16 + l15) * 96 + kk * 32 + l4 * 8];
#pragma unroll
      for (int nf = 0; nf < 2; nf++) {
        int p = (wv + ky) * 34 + (nf * 16 + l15 + kx);
        b[nf] = *(const bf16x8*)&stile[p * 104 + kk * 32 + l4 * 8];
      }
#pragma unroll
      for (int mf = 0; mf < 6; mf++)
#pragma unroll
        for (int nf = 0; nf < 2; nf++)
          acc[mf][nf] = __builtin_amdgcn_mfma_f32_16x16x32_bf16(a[mf], b[nf], acc[mf][nf], 0, 0, 0);
    }
  }
  int gy = y0 + wv;
  unsigned short* sT = stile;  // alias; stile dead after barrier
  __syncthreads();
#pragma unroll
  for (int mf = 0; mf < 6; mf++) {
#pragma unroll
    for (int nf = 0; nf < 2; nf++) {
      int lx = nf * 16 + l15;
      int p = wv * 32 + lx;
      ushort4v pk;
#pragma unroll
      for (int r = 0; r < 4; r++) {
        int oc = mf * 16 + l4 * 4 + r;
        size_t o = ((size_t)(n * 96 + oc)) * HW + gy * 128 + x0 + lx;
        float v = acc[mf][nf][r] + bias[oc] + high[o];
        pk[r] = f2bf(v);
      }
      *(ushort4v*)&sT[p * 104 + mf * 16 + l4 * 4] = pk;
    }
  }
  __syncthreads();
  for (int idx = t; idx < 1536; idx += 256) {
    int p = idx / 12, c8 = idx % 12;
    int py = p >> 5, lx = p & 31;
    size_t gpx = (size_t)n * HW + (y0 + py) * 128 + x0 + lx;
    *(ushort8*)&ehigh[gpx * 96 + c8 * 8] = *(ushort8*)&sT[p * 104 + c8 * 8];
  }
}

// ---------------- ff1: 1x1 192->192 MFMA, +bias, GN stats, bf16 t ----------------
__global__ __launch_bounds__(256) void k_ff1_mfma(const unsigned short* __restrict__ elow,
                                                  const unsigned short* __restrict__ ehigh,
                                                  const unsigned short* __restrict__ wbf,
                                                  const float* __restrict__ bias,
                                                  unsigned short* __restrict__ tbf,
                                                  float* __restrict__ ffstats) {
  __shared__ __align__(16) unsigned short sB[64 * 200];
  __shared__ float sred[4][8];
  int t = threadIdx.x;
  size_t pxbase = (size_t)blockIdx.x * 64;
  int n = blockIdx.x >> 8;  // 256 tiles per n
  for (int idx = t; idx < 1536; idx += 256) {
    int p = idx / 24, c8 = idx % 24;
    ushort8 v = (c8 < 12) ? *(const ushort8*)&elow[(pxbase + p) * 96 + c8 * 8]
                          : *(const ushort8*)&ehigh[(pxbase + p) * 96 + (c8 - 12) * 8];
    *(ushort8*)&sB[p * 200 + c8 * 8] = v;
  }
  __syncthreads();
  int wv = t >> 6, lane = t & 63, l15 = lane & 15, l4 = lane >> 4;
  f32x4 acc[12];
#pragma unroll
  for (int mf = 0; mf < 12; mf++) acc[mf] = (f32x4)0.f;
  const unsigned short* wp = wbf + l15 * 192 + l4 * 8;
  const unsigned short* bp = &sB[(wv * 16 + l15) * 200 + l4 * 8];
#pragma unroll
  for (int kk = 0; kk < 6; kk++) {
    bf16x8 b = *(const bf16x8*)(bp + kk * 32);
#pragma unroll
    for (int mf = 0; mf < 12; mf++) {
      bf16x8 a = *(const bf16x8*)(wp + mf * 3072 + kk * 32);
      acc[mf] = __builtin_amdgcn_mfma_f32_16x16x32_bf16(a, b, acc[mf], 0, 0, 0);
    }
  }
  // epilogue: bias, stats, pack into own rows of sB (each wave reads/writes only its rows)
  float s[4] = {0.f, 0.f, 0.f, 0.f}, ss[4] = {0.f, 0.f, 0.f, 0.f};
#pragma unroll
  for (int mf = 0; mf < 12; mf++) {
    int g = mf / 3;
    ushort4v pk;
#pragma unroll
    for (int r = 0; r < 4; r++) {
      float v = acc[mf][r] + bias[mf * 16 + l4 * 4 + r];
      s[g] += v;
      ss[g] += v * v;
      pk[r] = f2bf(v);
    }
    *(ushort4v*)&sB[(wv * 16 + l15) * 200 + mf * 16 + l4 * 4] = pk;
  }
#pragma unroll
  for (int g = 0; g < 4; g++) {
    s[g] = wave_sum(s[g]);
    ss[g] = wave_sum(ss[g]);
  }
  if (!lane) {
#pragma unroll
    for (int g = 0; g < 4; g++) {
      sred[wv][g] = s[g];
      sred[wv][4 + g] = ss[g];
    }
  }
  __syncthreads();
  for (int idx = t; idx < 1536; idx += 256) {
    int p = idx / 24, c8 = idx % 24;
    *(ushort8*)&tbf[(pxbase + p) * 192 + c8 * 8] = *(ushort8*)&sB[p * 200 + c8 * 8];
  }
  if (t < 8) {
    float tot = sred[0][t] + sred[1][t] + sred[2][t] + sred[3][t];
    atomicAdd(&ffstats[(n * 4 + (t & 3)) * 2 + (t >> 2)], tot);
  }
}

// ---------------- ff2: GN+GELU fused staging, 1x1 192->96 MFMA -> fp32 NCHW ----------------
__global__ __launch_bounds__(256) void k_ff2_mfma(const unsigned short* __restrict__ tbf,
                                                  const float* __restrict__ ffstats,
                                                  const float* __restrict__ gs,
                                                  const float* __restrict__ gb,
                                                  const unsigned short* __restrict__ wbf,
                                                  const float* __restrict__ bias,
                                                  float* __restrict__ out) {
  __shared__ __align__(16) unsigned short sB[64 * 200];
  int t = threadIdx.x;
  size_t pxbase = (size_t)blockIdx.x * 64;
  int n = blockIdx.x >> 8;
  float fm[4], fvv[4];
#pragma unroll
  for (int g = 0; g < 4; g++) {
    fm[g] = ffstats[(n * 4 + g) * 2];
    fvv[g] = ffstats[(n * 4 + g) * 2 + 1];
  }
  for (int idx = t; idx < 1536; idx += 256) {
    int p = idx / 24, c8 = idx % 24;
    int c = c8 * 8, g = c / 48;
    ushort8 raw = *(const ushort8*)&tbf[(pxbase + p) * 192 + c];
    ushort8 pk;
#pragma unroll
    for (int j = 0; j < 8; j++) {
      float rv = bf2f(raw[j]);
      float z = (rv - fm[g]) * fvv[g] * gs[c + j] + gb[c + j];
      float gl = 0.5f * z * (1.f + erff(z * 0.70710678118654752f));
      pk[j] = f2bf(gl);
    }
    *(ushort8*)&sB[p * 200 + c] = pk;
  }
  __syncthreads();
  int wv = t >> 6, lane = t & 63, l15 = lane & 15, l4 = lane >> 4;
  f32x4 acc[6];
#pragma unroll
  for (int mf = 0; mf < 6; mf++) acc[mf] = (f32x4)0.f;
  const unsigned short* wp = wbf + l15 * 192 + l4 * 8;
  const unsigned short* bp = &sB[(wv * 16 + l15) * 200 + l4 * 8];
#pragma unroll
  for (int kk = 0; kk < 6; kk++) {
    bf16x8 b = *(const bf16x8*)(bp + kk * 32);
#pragma unroll
    for (int mf = 0; mf < 6; mf++) {
      bf16x8 a = *(const bf16x8*)(wp + mf * 3072 + kk * 32);
      acc[mf] = __builtin_amdgcn_mfma_f32_16x16x32_bf16(a, b, acc[mf], 0, 0, 0);
    }
  }
  int lpx = (blockIdx.x & 255) * 64 + wv * 16 + l15;
#pragma unroll
  for (int mf = 0; mf < 6; mf++) {
#pragma unroll
    for (int r = 0; r < 4; r++) {
      int oc = mf * 16 + l4 * 4 + r;
      out[((size_t)(n * 96 + oc)) * HW + lpx] = acc[mf][r] + bias[oc];
    }
  }
}

extern "C" void kernel_launch(void* const* d_in, const int* in_sizes, int n_in,
                              void* d_out, int out_size, void* d_ws, size_t ws_size,
                              hipStream_t stream) {
  const float* x = (const float*)d_in[0];
  const float* cf_w = (const float*)d_in[1];
  const float* gnf_s = (const float*)d_in[2];
  const float* gnf_b = (const float*)d_in[3];
  const float* lb1_w = (const float*)d_in[4];
  const float* lb1_b = (const float*)d_in[5];
  const float* pr1 = (const float*)d_in[6];
  const float* lbd1_w = (const float*)d_in[7];
  const float* lbd1_b = (const float*)d_in[8];
  const float* lb2_w = (const float*)d_in[9];
  const float* lb2_b = (const float*)d_in[10];
  const float* pr2 = (const float*)d_in[11];
  const float* lbd2_w = (const float*)d_in[12];
  const float* lbd2_b = (const float*)d_in[13];
  const float* lb3_w = (const float*)d_in[14];
  const float* lb3_b = (const float*)d_in[15];
  const float* pr3 = (const float*)d_in[16];
  const float* lbd3_w = (const float*)d_in[17];
  const float* lbd3_b = (const float*)d_in[18];
  const float* lb4_w = (const float*)d_in[19];
  const float* lb4_b = (const float*)d_in[20];
  const float* pr4 = (const float*)d_in[21];
  const float* lb5_w = (const float*)d_in[22];
  const float* lb5_b = (const float*)d_in[23];
  const float* gnh_s = (const float*)d_in[24];
  const float* gnh_b = (const float*)d_in[25];
  const float* hb_w = (const float*)d_in[26];
  const float* hb_b = (const float*)d_in[27];
  const float* ff1_w = (const float*)d_in[28];
  const float* ff1_b = (const float*)d_in[29];
  const float* gnff_s = (const float*)d_in[30];
  const float* gnff_b = (const float*)d_in[31];
  const float* ff2_w = (const float*)d_in[32];
  const float* ff2_b = (const float*)d_in[33];

  const size_t SPC = (size_t)8 * 96 * HW;  // 12,582,912 floats
  const size_t YSZ = (size_t)8 * 24 * HW;
  float* ws = (float*)d_ws;
  float* buf_low = ws;                                   // fp32 NCHW; dead after lb1
  unsigned short* buf_tbf = (unsigned short*)ws;         // bf16 [px][192]; reuses buf_low
  float* buf_high = ws + SPC;                            // fp32 NCHW
  unsigned short* buf_hn = (unsigned short*)(ws + 2 * SPC);            // bf16 [px][96]
  unsigned short* buf_ehigh = (unsigned short*)(ws + 2 * SPC + SPC / 2);  // bf16 [px][96]
  unsigned short* buf_elow = (unsigned short*)(ws + 3 * SPC);          // bf16 [px][96]
  unsigned short* buf_wbf = (unsigned short*)(ws + 3 * SPC + SPC / 2);  // hb w, 82944
  unsigned short* buf_wff1 = buf_wbf + 82944;                           // 36864
  unsigned short* buf_wff2 = buf_wff1 + 36864;                          // 18432
  float* buf_y1 = ws + 4 * SPC;
  float* buf_y2 = buf_y1 + YSZ;
  float* buf_fi = buf_y2 + YSZ;      // 768
  float* buf_filt = buf_fi + 768;    // 6912
  float* buf_hst = buf_filt + 6912;  // 64
  float* buf_ffst = buf_hst + 64;    // 64

  hipMemsetAsync(buf_hst, 0, 128 * sizeof(float), stream);

  k_mean<<<768, 256, 0, stream>>>(x, buf_fi);
  k_filter<<<8, 256, 0, stream>>>(buf_fi, cf_w, gnf_s, gnf_b, buf_filt);
  k_invol<<<dim3(64, 768), 256, 0, stream>>>(x, buf_filt, buf_low, buf_high);

  k_conv1x1<96, 24, true><<<dim3(64, 8), 256, 0, stream>>>(buf_low, lb1_w, lb1_b, pr1, buf_y1);
  k_dw3x3<5><<<dim3(64, 192), 256, 0, stream>>>(buf_y1, lbd1_w, lbd1_b, buf_y2);
  k_conv1x1<24, 24, true><<<dim3(64, 8), 256, 0, stream>>>(buf_y2, lb2_w, lb2_b, pr2, buf_y1);
  k_dw3x3<1><<<dim3(64, 192), 256, 0, stream>>>(buf_y1, lbd2_w, lbd2_b, buf_y2);
  k_conv1x1<24, 24, true><<<dim3(64, 8), 256, 0, stream>>>(buf_y2, lb3_w, lb3_b, pr3, buf_y1);
  k_dw3x3<3><<<dim3(64, 192), 256, 0, stream>>>(buf_y1, lbd3_w, lbd3_b, buf_y2);
  k_conv1x1<24, 24, true><<<dim3(64, 8), 256, 0, stream>>>(buf_y2, lb4_w, lb4_b, pr4, buf_y1);
  k_lb5<<<dim3(64, 8), 256, 0, stream>>>(buf_y1, lb5_w, lb5_b, buf_elow);

  k_gnhigh_part<<<dim3(32, 8), 256, 0, stream>>>(buf_high, buf_hst);
  k_gnfin<<<1, 32, 0, stream>>>(buf_hst, 1.f / 393216.f);
  k_prep_w<<<324, 256, 0, stream>>>(hb_w, buf_wbf);
  k_prep_ffw<<<216, 256, 0, stream>>>(ff1_w, ff2_w, buf_wff1, buf_wff2);
  k_prep_hn<<<dim3(256, 8), 256, 0, stream>>>(buf_high, buf_hst, gnh_s, gnh_b, buf_hn);
  k_hbconv_mfma<<<dim3(4, 32, 8), 256, 0, stream>>>(buf_hn, buf_wbf, hb_b, buf_high, buf_ehigh);

  k_ff1_mfma<<<2048, 256, 0, stream>>>(buf_elow, buf_ehigh, buf_wff1, ff1_b, buf_tbf, buf_ffst);
  k_gnfin<<<1, 32, 0, stream>>>(buf_ffst, 1.f / 786432.f);
  k_ff2_mfma<<<2048, 256, 0, stream>>>(buf_tbf, buf_ffst, gnff_s, gnff_b, buf_wff2, ff2_b,
                                       (float*)d_out);
}

// Round 6
// 689.228 us; speedup vs baseline: 4.4680x; 1.0265x over previous
//
#include <hip/hip_runtime.h>
#include <math.h>

#define HW 16384
#define WIDTH 128

typedef short bf16x8 __attribute__((ext_vector_type(8)));
typedef float f32x4 __attribute__((ext_vector_type(4)));
typedef unsigned short ushort8 __attribute__((ext_vector_type(8)));
typedef unsigned short ushort4v __attribute__((ext_vector_type(4)));
typedef unsigned short ushort2v __attribute__((ext_vector_type(2)));

__device__ __forceinline__ float wave_sum(float v) {
#pragma unroll
  for (int o = 32; o > 0; o >>= 1) v += __shfl_down(v, o, 64);
  return v;
}

__device__ __forceinline__ unsigned short f2bf(float f) {
  unsigned u = __float_as_uint(f);
  return (unsigned short)((u + 0x7fffu + ((u >> 16) & 1u)) >> 16);
}

__device__ __forceinline__ float bf2f(unsigned short s) {
  return __uint_as_float((unsigned)s << 16);
}

// exact-GELU via branchless A&S 7.1.26 erf (abs err <= 1.5e-7)
__device__ __forceinline__ float gelu_exact(float z) {
  float u = z * 0.70710678118654752f;
  float ax = fabsf(u);
  float t = __builtin_amdgcn_rcpf(fmaf(0.3275911f, ax, 1.0f));
  float poly = t * fmaf(t, fmaf(t, fmaf(t, fmaf(t, 1.061405429f, -1.453152027f),
                                        1.421413741f), -0.284496736f), 0.254829592f);
  float e = __expf(-ax * ax);
  float erf_abs = fmaf(-poly, e, 1.0f);
  float erf = copysignf(erf_abs, z);
  return 0.5f * z * (1.0f + erf);
}

// ---------------- fi = mean over H,W ----------------
__global__ __launch_bounds__(256) void k_mean(const float* __restrict__ x,
                                              float* __restrict__ fi) {
  __shared__ float sm[4];
  int nc = blockIdx.x;  // 0..767
  const float4* p = (const float4*)(x + (size_t)nc * HW);
  float s = 0.f;
  for (int i = threadIdx.x; i < HW / 4; i += 256) {
    float4 v = p[i];
    s += (v.x + v.y) + (v.z + v.w);
  }
  s = wave_sum(s);
  int wid = threadIdx.x >> 6, lane = threadIdx.x & 63;
  if (!lane) sm[wid] = s;
  __syncthreads();
  if (!threadIdx.x) fi[nc] = (sm[0] + sm[1] + sm[2] + sm[3]) * (1.f / 16384.f);
}

// ---------------- dynamic filter: 1x1 conv -> GN(4 groups) -> softmax(9) ----------------
__global__ __launch_bounds__(256) void k_filter(const float* __restrict__ fi,
                                                const float* __restrict__ cf_w,
                                                const float* __restrict__ gnf_s,
                                                const float* __restrict__ gnf_b,
                                                float* __restrict__ filt) {
  int n = blockIdx.x;
  int t = threadIdx.x;
  __shared__ __align__(16) float sfi[96];
  __shared__ float sfw[864];
  __shared__ float gstat[8];
  if (t < 96) sfi[t] = fi[n * 96 + t];
  __syncthreads();
  for (int oc = t; oc < 864; oc += 256) {
    const float4* wr = (const float4*)(cf_w + (size_t)oc * 96);
    const float4* fr = (const float4*)sfi;
    float a = 0.f;
#pragma unroll
    for (int q = 0; q < 24; q++) {
      float4 w4 = wr[q];
      float4 f4 = fr[q];
      a += w4.x * f4.x + w4.y * f4.y + w4.z * f4.z + w4.w * f4.w;
    }
    sfw[oc] = a;
  }
  __syncthreads();
  if (t < 4) {
    float s = 0.f, ss = 0.f;
    for (int i = 0; i < 216; i++) {
      float v = sfw[t * 216 + i];
      s += v;
      ss += v * v;
    }
    float m = s * (1.f / 216.f);
    float var = ss * (1.f / 216.f) - m * m;
    gstat[t * 2] = m;
    gstat[t * 2 + 1] = rsqrtf(var + 1e-5f);
  }
  __syncthreads();
  for (int oc = t; oc < 864; oc += 256) {
    int g = oc / 216;
    sfw[oc] = (sfw[oc] - gstat[g * 2]) * gstat[g * 2 + 1] * gnf_s[oc] + gnf_b[oc];
  }
  __syncthreads();
  if (t < 96) {
    float v[9], mx = -1e30f;
#pragma unroll
    for (int k = 0; k < 9; k++) {
      v[k] = sfw[t * 9 + k];
      mx = fmaxf(mx, v[k]);
    }
    float s = 0.f;
#pragma unroll
    for (int k = 0; k < 9; k++) {
      v[k] = expf(v[k] - mx);
      s += v[k];
    }
    float inv = 1.f / s;
#pragma unroll
    for (int k = 0; k < 9; k++) filt[((size_t)n * 96 + t) * 9 + k] = v[k] * inv;
  }
}

// ---------------- involution (reflect pad, taps {-2,0,2}) + high = x - low ----------------
__global__ __launch_bounds__(256) void k_invol(const float* __restrict__ x,
                                               const float* __restrict__ filt,
                                               float* __restrict__ low,
                                               float* __restrict__ high) {
  int nc = blockIdx.y;
  const float* xp = x + (size_t)nc * HW;
  const float* fp = filt + (size_t)nc * 9;
  float f[9];
#pragma unroll
  for (int k = 0; k < 9; k++) f[k] = fp[k];
  int idx = blockIdx.x * 256 + threadIdx.x;
  int y = idx >> 7, xx = idx & 127;
  int ry[3], rx[3];
#pragma unroll
  for (int d = 0; d < 3; d++) {
    int p = y + 2 * d - 2;
    if (p < 0) p = -p;
    if (p > 127) p = 254 - p;
    ry[d] = p;
    int q = xx + 2 * d - 2;
    if (q < 0) q = -q;
    if (q > 127) q = 254 - q;
    rx[d] = q;
  }
  float acc = 0.f;
#pragma unroll
  for (int i = 0; i < 3; i++)
#pragma unroll
    for (int j = 0; j < 3; j++) acc = fmaf(f[i * 3 + j], xp[ry[i] * WIDTH + rx[j]], acc);
  float xv = xp[idx];
  size_t o = (size_t)nc * HW + idx;
  low[o] = acc;
  high[o] = xv - acc;
}

// ---------------- generic 1x1 conv (+bias, optional PReLU) ----------------
template <int CIN, int COUT, bool PRELU>
__global__ __launch_bounds__(256) void k_conv1x1(const float* __restrict__ in,
                                                 const float* __restrict__ w,
                                                 const float* __restrict__ b,
                                                 const float* __restrict__ pr,
                                                 float* __restrict__ out) {
  int n = blockIdx.y;
  int pix = blockIdx.x * 256 + threadIdx.x;
  const float* ip = in + (size_t)n * CIN * HW + pix;
  float acc[COUT];
#pragma unroll
  for (int o = 0; o < COUT; o++) acc[o] = b[o];
  for (int c = 0; c < CIN; c += 4) {
    float v0 = ip[(size_t)c * HW];
    float v1 = ip[(size_t)(c + 1) * HW];
    float v2 = ip[(size_t)(c + 2) * HW];
    float v3 = ip[(size_t)(c + 3) * HW];
#pragma unroll
    for (int o = 0; o < COUT; o++) {
      float4 wv = *(const float4*)(w + (size_t)o * CIN + c);
      acc[o] = fmaf(v0, wv.x, acc[o]);
      acc[o] = fmaf(v1, wv.y, acc[o]);
      acc[o] = fmaf(v2, wv.z, acc[o]);
      acc[o] = fmaf(v3, wv.w, acc[o]);
    }
  }
  float a = PRELU ? pr[0] : 0.f;
  float* op = out + (size_t)n * COUT * HW + pix;
#pragma unroll
  for (int o = 0; o < COUT; o++) {
    float v = acc[o];
    if (PRELU) v = v >= 0.f ? v : a * v;
    op[(size_t)o * HW] = v;
  }
}

// ---------------- fused: depthwise 3x3 (zero pad = dil) + 1x1 24->24 + PReLU ----------------
template <int DILA>
__global__ __launch_bounds__(256) void k_dwfuse(const float* __restrict__ in,
                                                const float* __restrict__ dw,
                                                const float* __restrict__ dwb,
                                                const float* __restrict__ w1,
                                                const float* __restrict__ b1,
                                                const float* __restrict__ pr,
                                                float* __restrict__ out) {
  int n = blockIdx.y;
  int pix = blockIdx.x * 256 + threadIdx.x;
  int y = pix >> 7, xx = pix & 127;
  const float* ip = in + (size_t)n * 24 * HW;
  float acc[24];
#pragma unroll
  for (int o = 0; o < 24; o++) acc[o] = b1[o];
  for (int c = 0; c < 24; c += 4) {
    float d[4];
#pragma unroll
    for (int q = 0; q < 4; q++) {
      float a = dwb[c + q];
      const float* cp = ip + (size_t)(c + q) * HW;
#pragma unroll
      for (int i = 0; i < 3; i++) {
        int yy = y + DILA * (i - 1);
        if (yy < 0 || yy >= 128) continue;
#pragma unroll
        for (int j = 0; j < 3; j++) {
          int xj = xx + DILA * (j - 1);
          if (xj < 0 || xj >= 128) continue;
          a = fmaf(dw[(c + q) * 9 + i * 3 + j], cp[yy * WIDTH + xj], a);
        }
      }
      d[q] = a;
    }
#pragma unroll
    for (int o = 0; o < 24; o++) {
      float4 wv = *(const float4*)(w1 + (size_t)o * 24 + c);
      acc[o] = fmaf(d[0], wv.x, acc[o]);
      acc[o] = fmaf(d[1], wv.y, acc[o]);
      acc[o] = fmaf(d[2], wv.z, acc[o]);
      acc[o] = fmaf(d[3], wv.w, acc[o]);
    }
  }
  float a = pr[0];
  float* op = out + (size_t)n * 24 * HW + pix;
#pragma unroll
  for (int o = 0; o < 24; o++) {
    float v = acc[o];
    op[(size_t)o * HW] = v >= 0.f ? v : a * v;
  }
}

// ---------------- lb5: 1x1 24->96, writes bf16 NHWC ----------------
__global__ __launch_bounds__(256) void k_lb5(const float* __restrict__ in,
                                             const float* __restrict__ w,
                                             const float* __restrict__ b,
                                             unsigned short* __restrict__ out) {
  int n = blockIdx.y;
  int pix = blockIdx.x * 256 + threadIdx.x;
  const float* ip = in + (size_t)n * 24 * HW + pix;
  float acc[96];
#pragma unroll
  for (int o = 0; o < 96; o++) acc[o] = b[o];
  for (int c = 0; c < 24; c += 4) {
    float v0 = ip[(size_t)c * HW];
    float v1 = ip[(size_t)(c + 1) * HW];
    float v2 = ip[(size_t)(c + 2) * HW];
    float v3 = ip[(size_t)(c + 3) * HW];
#pragma unroll
    for (int o = 0; o < 96; o++) {
      float4 wv = *(const float4*)(w + (size_t)o * 24 + c);
      acc[o] = fmaf(v0, wv.x, acc[o]);
      acc[o] = fmaf(v1, wv.y, acc[o]);
      acc[o] = fmaf(v2, wv.z, acc[o]);
      acc[o] = fmaf(v3, wv.w, acc[o]);
    }
  }
  unsigned short* op = out + ((size_t)n * HW + pix) * 96;
#pragma unroll
  for (int c8 = 0; c8 < 12; c8++) {
    ushort8 pk;
#pragma unroll
    for (int j = 0; j < 8; j++) pk[j] = f2bf(acc[c8 * 8 + j]);
    *(ushort8*)&op[c8 * 8] = pk;
  }
}

// ---------------- GN stats for high: partial sums (atomic) ----------------
__global__ __launch_bounds__(256) void k_gnhigh_part(const float* __restrict__ h,
                                                     float* __restrict__ stats) {
  int ng = blockIdx.x;  // n*4+g, region = 24*HW contiguous
  const float4* p = (const float4*)(h + (size_t)ng * 393216 + (size_t)blockIdx.y * 49152);
  float s = 0.f, ss = 0.f;
  for (int i = threadIdx.x; i < 12288; i += 256) {
    float4 v = p[i];
    s += (v.x + v.y) + (v.z + v.w);
    ss += (v.x * v.x + v.y * v.y) + (v.z * v.z + v.w * v.w);
  }
  s = wave_sum(s);
  ss = wave_sum(ss);
  __shared__ float sm[8];
  int wid = threadIdx.x >> 6, lane = threadIdx.x & 63;
  if (!lane) {
    sm[wid] = s;
    sm[4 + wid] = ss;
  }
  __syncthreads();
  if (!threadIdx.x) {
    atomicAdd(&stats[ng * 2], sm[0] + sm[1] + sm[2] + sm[3]);
    atomicAdd(&stats[ng * 2 + 1], sm[4] + sm[5] + sm[6] + sm[7]);
  }
}

// ---------------- finalize GN stats: sum,sumsq -> mean,invstd ----------------
__global__ void k_gnfin(float* stats, float inv_cnt) {
  int i = threadIdx.x;  // 32 = n*groups
  float s = stats[i * 2], ss = stats[i * 2 + 1];
  float m = s * inv_cnt;
  float var = ss * inv_cnt - m * m;
  stats[i * 2] = m;
  stats[i * 2 + 1] = rsqrtf(var + 1e-5f);
}

// ---------------- prep: GN+leaky on high -> bf16, transpose to [n][y][x][cin] ----------------
__global__ __launch_bounds__(256) void k_prep_hn(const float* __restrict__ high,
                                                 const float* __restrict__ hstats,
                                                 const float* __restrict__ gs,
                                                 const float* __restrict__ gb,
                                                 unsigned short* __restrict__ hn) {
  __shared__ unsigned short sm[64 * 104];
  int n = blockIdx.y;
  int px0 = blockIdx.x * 64;
  int t = threadIdx.x;
  int px = t & 63, cg = t >> 6;  // cg 0..3
  float hm[4], hi[4];
#pragma unroll
  for (int g = 0; g < 4; g++) {
    hm[g] = hstats[(n * 4 + g) * 2];
    hi[g] = hstats[(n * 4 + g) * 2 + 1];
  }
#pragma unroll
  for (int c0 = 0; c0 < 96; c0 += 8) {
    int c = c0 + cg * 2;
    int g = c / 24;
    float v0 = high[((size_t)(n * 96 + c)) * HW + px0 + px];
    float v1 = high[((size_t)(n * 96 + c + 1)) * HW + px0 + px];
    float h0 = (v0 - hm[g]) * hi[g] * gs[c] + gb[c];
    float h1 = (v1 - hm[g]) * hi[g] * gs[c + 1] + gb[c + 1];
    h0 = h0 >= 0.f ? h0 : 0.01f * h0;
    h1 = h1 >= 0.f ? h1 : 0.01f * h1;
    ushort2v p;
    p.x = f2bf(h0);
    p.y = f2bf(h1);
    *(ushort2v*)&sm[px * 104 + c] = p;
  }
  __syncthreads();
#pragma unroll
  for (int k = 0; k < 3; k++) {
    int idx = t + k * 256;  // 768 chunks
    int p = idx / 12, c8 = idx % 12;
    ushort8 v = *(ushort8*)&sm[p * 104 + c8 * 8];
    *(ushort8*)&hn[((size_t)n * HW + px0 + p) * 96 + c8 * 8] = v;
  }
}

// ---------------- prep: hb weights fp32 [oc][cin][3][3] -> bf16 [tap][oc][cin] ----------------
__global__ __launch_bounds__(256) void k_prep_w(const float* __restrict__ w,
                                                unsigned short* __restrict__ wbf) {
  int i = blockIdx.x * 256 + threadIdx.x;  // 82944
  int tap = i / 9216;
  int r = i - tap * 9216;
  int oc = r / 96, cin = r - oc * 96;
  wbf[i] = f2bf(w[(size_t)(oc * 96 + cin) * 9 + tap]);
}

// ---------------- prep: ff1/ff2 weights -> bf16 (same [oc][cin] layout) ----------------
__global__ __launch_bounds__(256) void k_prep_ffw(const float* __restrict__ w1,
                                                  const float* __restrict__ w2,
                                                  unsigned short* __restrict__ o1,
                                                  unsigned short* __restrict__ o2) {
  int i = blockIdx.x * 256 + threadIdx.x;  // 55296
  if (i < 36864)
    o1[i] = f2bf(w1[i]);
  else
    o2[i - 36864] = f2bf(w2[i - 36864]);
}

// ---------------- hb 3x3 conv 96->96 implicit-GEMM MFMA + bias + residual -> bf16 NHWC ----
__global__ __launch_bounds__(256) void k_hbconv_mfma(const unsigned short* __restrict__ hn,
                                                     const unsigned short* __restrict__ wbf,
                                                     const float* __restrict__ bias,
                                                     const float* __restrict__ high,
                                                     unsigned short* __restrict__ ehigh) {
  // grid (4 xt, 32 yt, 8 n); block 256 = 4 waves. Tile: 96 oc x (4y x 32x) px.
  __shared__ __align__(16) unsigned short stile[6 * 34 * 104];  // also reused as sT[128][104]
  int t = threadIdx.x;
  int n = blockIdx.z;
  int x0 = blockIdx.x * 32, y0 = blockIdx.y * 4;
  for (int idx = t; idx < 2448; idx += 256) {
    int p = idx / 12, c8 = idx % 12;
    int ly = p / 34, lx = p - ly * 34;
    int gy = y0 + ly - 1, gx = x0 + lx - 1;
    ushort8 v = (ushort8)0;
    if ((unsigned)gy < 128u && (unsigned)gx < 128u)
      v = *(const ushort8*)&hn[((size_t)n * HW + gy * 128 + gx) * 96 + c8 * 8];
    *(ushort8*)&stile[(ly * 34 + lx) * 104 + c8 * 8] = v;
  }
  __syncthreads();
  int wv = t >> 6;  // wave = y row of tile
  int lane = t & 63;
  int l15 = lane & 15, l4 = lane >> 4;
  f32x4 acc[6][2];
#pragma unroll
  for (int mf = 0; mf < 6; mf++)
#pragma unroll
    for (int nf = 0; nf < 2; nf++) acc[mf][nf] = (f32x4)0.f;
#pragma unroll 1
  for (int tap = 0; tap < 9; tap++) {
    int ky = tap / 3, kx = tap - ky * 3;
    const unsigned short* wt = wbf + (size_t)tap * 9216;
#pragma unroll
    for (int kk = 0; kk < 3; kk++) {
      bf16x8 a[6], b[2];
#pragma unroll
      for (int mf = 0; mf < 6; mf++)
        a[mf] = *(const bf16x8*)&wt[(mf * 16 + l15) * 96 + kk * 32 + l4 * 8];
#pragma unroll
      for (int nf = 0; nf < 2; nf++) {
        int p = (wv + ky) * 34 + (nf * 16 + l15 + kx);
        b[nf] = *(const bf16x8*)&stile[p * 104 + kk * 32 + l4 * 8];
      }
#pragma unroll
      for (int mf = 0; mf < 6; mf++)
#pragma unroll
        for (int nf = 0; nf < 2; nf++)
          acc[mf][nf] = __builtin_amdgcn_mfma_f32_16x16x32_bf16(a[mf], b[nf], acc[mf][nf], 0, 0, 0);
    }
  }
  int gy = y0 + wv;
  unsigned short* sT = stile;  // alias; stile dead after barrier
  __syncthreads();
#pragma unroll
  for (int mf = 0; mf < 6; mf++) {
#pragma unroll
    for (int nf = 0; nf < 2; nf++) {
      int lx = nf * 16 + l15;
      int p = wv * 32 + lx;
      ushort4v pk;
#pragma unroll
      for (int r = 0; r < 4; r++) {
        int oc = mf * 16 + l4 * 4 + r;
        size_t o = ((size_t)(n * 96 + oc)) * HW + gy * 128 + x0 + lx;
        float v = acc[mf][nf][r] + bias[oc] + high[o];
        pk[r] = f2bf(v);
      }
      *(ushort4v*)&sT[p * 104 + mf * 16 + l4 * 4] = pk;
    }
  }
  __syncthreads();
  for (int idx = t; idx < 1536; idx += 256) {
    int p = idx / 12, c8 = idx % 12;
    int py = p >> 5, lx = p & 31;
    size_t gpx = (size_t)n * HW + (y0 + py) * 128 + x0 + lx;
    *(ushort8*)&ehigh[gpx * 96 + c8 * 8] = *(ushort8*)&sT[p * 104 + c8 * 8];
  }
}

// ---------------- ff1: 1x1 192->192 MFMA, +bias, GN stats, bf16 t ----------------
__global__ __launch_bounds__(256) void k_ff1_mfma(const unsigned short* __restrict__ elow,
                                                  const unsigned short* __restrict__ ehigh,
                                                  const unsigned short* __restrict__ wbf,
                                                  const float* __restrict__ bias,
                                                  unsigned short* __restrict__ tbf,
                                                  float* __restrict__ ffstats) {
  __shared__ __align__(16) unsigned short sB[64 * 200];
  __shared__ float sred[4][8];
  int t = threadIdx.x;
  size_t pxbase = (size_t)blockIdx.x * 64;
  int n = blockIdx.x >> 8;  // 256 tiles per n
  for (int idx = t; idx < 1536; idx += 256) {
    int p = idx / 24, c8 = idx % 24;
    ushort8 v = (c8 < 12) ? *(const ushort8*)&elow[(pxbase + p) * 96 + c8 * 8]
                          : *(const ushort8*)&ehigh[(pxbase + p) * 96 + (c8 - 12) * 8];
    *(ushort8*)&sB[p * 200 + c8 * 8] = v;
  }
  __syncthreads();
  int wv = t >> 6, lane = t & 63, l15 = lane & 15, l4 = lane >> 4;
  f32x4 acc[12];
#pragma unroll
  for (int mf = 0; mf < 12; mf++) acc[mf] = (f32x4)0.f;
  const unsigned short* wp = wbf + l15 * 192 + l4 * 8;
  const unsigned short* bp = &sB[(wv * 16 + l15) * 200 + l4 * 8];
#pragma unroll
  for (int kk = 0; kk < 6; kk++) {
    bf16x8 b = *(const bf16x8*)(bp + kk * 32);
#pragma unroll
    for (int mf = 0; mf < 12; mf++) {
      bf16x8 a = *(const bf16x8*)(wp + mf * 3072 + kk * 32);
      acc[mf] = __builtin_amdgcn_mfma_f32_16x16x32_bf16(a, b, acc[mf], 0, 0, 0);
    }
  }
  // epilogue: bias, stats, pack into own rows of sB (each wave reads/writes only its rows)
  float s[4] = {0.f, 0.f, 0.f, 0.f}, ss[4] = {0.f, 0.f, 0.f, 0.f};
#pragma unroll
  for (int mf = 0; mf < 12; mf++) {
    int g = mf / 3;
    ushort4v pk;
#pragma unroll
    for (int r = 0; r < 4; r++) {
      float v = acc[mf][r] + bias[mf * 16 + l4 * 4 + r];
      s[g] += v;
      ss[g] += v * v;
      pk[r] = f2bf(v);
    }
    *(ushort4v*)&sB[(wv * 16 + l15) * 200 + mf * 16 + l4 * 4] = pk;
  }
#pragma unroll
  for (int g = 0; g < 4; g++) {
    s[g] = wave_sum(s[g]);
    ss[g] = wave_sum(ss[g]);
  }
  if (!lane) {
#pragma unroll
    for (int g = 0; g < 4; g++) {
      sred[wv][g] = s[g];
      sred[wv][4 + g] = ss[g];
    }
  }
  __syncthreads();
  for (int idx = t; idx < 1536; idx += 256) {
    int p = idx / 24, c8 = idx % 24;
    *(ushort8*)&tbf[(pxbase + p) * 192 + c8 * 8] = *(ushort8*)&sB[p * 200 + c8 * 8];
  }
  if (t < 8) {
    float tot = sred[0][t] + sred[1][t] + sred[2][t] + sred[3][t];
    atomicAdd(&ffstats[(n * 4 + (t & 3)) * 2 + (t >> 2)], tot);
  }
}

// ---------------- ff2: GN+GELU fused staging (prefetched), 1x1 192->96 MFMA -> fp32 NCHW ----
__global__ __launch_bounds__(256) void k_ff2_mfma(const unsigned short* __restrict__ tbf,
                                                  const float* __restrict__ ffstats,
                                                  const float* __restrict__ gs,
                                                  const float* __restrict__ gb,
                                                  const unsigned short* __restrict__ wbf,
                                                  const float* __restrict__ bias,
                                                  float* __restrict__ out) {
  __shared__ __align__(16) unsigned short sB[64 * 200];
  int t = threadIdx.x;
  size_t pxbase = (size_t)blockIdx.x * 64;
  int n = blockIdx.x >> 8;
  float fm[4], fvv[4];
#pragma unroll
  for (int g = 0; g < 4; g++) {
    fm[g] = ffstats[(n * 4 + g) * 2];
    fvv[g] = ffstats[(n * 4 + g) * 2 + 1];
  }
  // prefetch all 6 staging chunks first (overlap VMEM latency), then compute
  ushort8 raw[6];
  int pp[6], cc[6];
#pragma unroll
  for (int k = 0; k < 6; k++) {
    int idx = t + k * 256;
    int p = idx / 24, c8 = idx - p * 24;
    pp[k] = p;
    cc[k] = c8 * 8;
    raw[k] = *(const ushort8*)&tbf[(pxbase + p) * 192 + cc[k]];
  }
#pragma unroll
  for (int k = 0; k < 6; k++) {
    int c = cc[k], g = c / 48;
    ushort8 pk;
#pragma unroll
    for (int j = 0; j < 8; j++) {
      float rv = bf2f(raw[k][j]);
      float z = (rv - fm[g]) * fvv[g] * gs[c + j] + gb[c + j];
      pk[j] = f2bf(gelu_exact(z));
    }
    *(ushort8*)&sB[pp[k] * 200 + c] = pk;
  }
  __syncthreads();
  int wv = t >> 6, lane = t & 63, l15 = lane & 15, l4 = lane >> 4;
  f32x4 acc[6];
#pragma unroll
  for (int mf = 0; mf < 6; mf++) acc[mf] = (f32x4)0.f;
  const unsigned short* wp = wbf + l15 * 192 + l4 * 8;
  const unsigned short* bp = &sB[(wv * 16 + l15) * 200 + l4 * 8];
#pragma unroll
  for (int kk = 0; kk < 6; kk++) {
    bf16x8 b = *(const bf16x8*)(bp + kk * 32);
#pragma unroll
    for (int mf = 0; mf < 6; mf++) {
      bf16x8 a = *(const bf16x8*)(wp + mf * 3072 + kk * 32);
      acc[mf] = __builtin_amdgcn_mfma_f32_16x16x32_bf16(a, b, acc[mf], 0, 0, 0);
    }
  }
  int lpx = (blockIdx.x & 255) * 64 + wv * 16 + l15;
#pragma unroll
  for (int mf = 0; mf < 6; mf++) {
#pragma unroll
    for (int r = 0; r < 4; r++) {
      int oc = mf * 16 + l4 * 4 + r;
      out[((size_t)(n * 96 + oc)) * HW + lpx] = acc[mf][r] + bias[oc];
    }
  }
}

extern "C" void kernel_launch(void* const* d_in, const int* in_sizes, int n_in,
                              void* d_out, int out_size, void* d_ws, size_t ws_size,
                              hipStream_t stream) {
  const float* x = (const float*)d_in[0];
  const float* cf_w = (const float*)d_in[1];
  const float* gnf_s = (const float*)d_in[2];
  const float* gnf_b = (const float*)d_in[3];
  const float* lb1_w = (const float*)d_in[4];
  const float* lb1_b = (const float*)d_in[5];
  const float* pr1 = (const float*)d_in[6];
  const float* lbd1_w = (const float*)d_in[7];
  const float* lbd1_b = (const float*)d_in[8];
  const float* lb2_w = (const float*)d_in[9];
  const float* lb2_b = (const float*)d_in[10];
  const float* pr2 = (const float*)d_in[11];
  const float* lbd2_w = (const float*)d_in[12];
  const float* lbd2_b = (const float*)d_in[13];
  const float* lb3_w = (const float*)d_in[14];
  const float* lb3_b = (const float*)d_in[15];
  const float* pr3 = (const float*)d_in[16];
  const float* lbd3_w = (const float*)d_in[17];
  const float* lbd3_b = (const float*)d_in[18];
  const float* lb4_w = (const float*)d_in[19];
  const float* lb4_b = (const float*)d_in[20];
  const float* pr4 = (const float*)d_in[21];
  const float* lb5_w = (const float*)d_in[22];
  const float* lb5_b = (const float*)d_in[23];
  const float* gnh_s = (const float*)d_in[24];
  const float* gnh_b = (const float*)d_in[25];
  const float* hb_w = (const float*)d_in[26];
  const float* hb_b = (const float*)d_in[27];
  const float* ff1_w = (const float*)d_in[28];
  const float* ff1_b = (const float*)d_in[29];
  const float* gnff_s = (const float*)d_in[30];
  const float* gnff_b = (const float*)d_in[31];
  const float* ff2_w = (const float*)d_in[32];
  const float* ff2_b = (const float*)d_in[33];

  const size_t SPC = (size_t)8 * 96 * HW;  // 12,582,912 floats
  const size_t YSZ = (size_t)8 * 24 * HW;
  float* ws = (float*)d_ws;
  float* buf_low = ws;                                   // fp32 NCHW; dead after lb1
  unsigned short* buf_tbf = (unsigned short*)ws;         // bf16 [px][192]; reuses buf_low
  float* buf_high = ws + SPC;                            // fp32 NCHW
  unsigned short* buf_hn = (unsigned short*)(ws + 2 * SPC);            // bf16 [px][96]
  unsigned short* buf_ehigh = (unsigned short*)(ws + 2 * SPC + SPC / 2);  // bf16 [px][96]
  unsigned short* buf_elow = (unsigned short*)(ws + 3 * SPC);          // bf16 [px][96]
  unsigned short* buf_wbf = (unsigned short*)(ws + 3 * SPC + SPC / 2);  // hb w, 82944
  unsigned short* buf_wff1 = buf_wbf + 82944;                           // 36864
  unsigned short* buf_wff2 = buf_wff1 + 36864;                          // 18432
  float* buf_y1 = ws + 4 * SPC;
  float* buf_y2 = buf_y1 + YSZ;
  float* buf_fi = buf_y2 + YSZ;      // 768
  float* buf_filt = buf_fi + 768;    // 6912
  float* buf_hst = buf_filt + 6912;  // 64
  float* buf_ffst = buf_hst + 64;    // 64

  hipMemsetAsync(buf_hst, 0, 128 * sizeof(float), stream);

  k_mean<<<768, 256, 0, stream>>>(x, buf_fi);
  k_filter<<<8, 256, 0, stream>>>(buf_fi, cf_w, gnf_s, gnf_b, buf_filt);
  k_invol<<<dim3(64, 768), 256, 0, stream>>>(x, buf_filt, buf_low, buf_high);

  k_conv1x1<96, 24, true><<<dim3(64, 8), 256, 0, stream>>>(buf_low, lb1_w, lb1_b, pr1, buf_y1);
  k_dwfuse<5><<<dim3(64, 8), 256, 0, stream>>>(buf_y1, lbd1_w, lbd1_b, lb2_w, lb2_b, pr2,
                                               buf_y2);
  k_dwfuse<1><<<dim3(64, 8), 256, 0, stream>>>(buf_y2, lbd2_w, lbd2_b, lb3_w, lb3_b, pr3,
                                               buf_y1);
  k_dwfuse<3><<<dim3(64, 8), 256, 0, stream>>>(buf_y1, lbd3_w, lbd3_b, lb4_w, lb4_b, pr4,
                                               buf_y2);
  k_lb5<<<dim3(64, 8), 256, 0, stream>>>(buf_y2, lb5_w, lb5_b, buf_elow);

  k_gnhigh_part<<<dim3(32, 8), 256, 0, stream>>>(buf_high, buf_hst);
  k_gnfin<<<1, 32, 0, stream>>>(buf_hst, 1.f / 393216.f);
  k_prep_w<<<324, 256, 0, stream>>>(hb_w, buf_wbf);
  k_prep_ffw<<<216, 256, 0, stream>>>(ff1_w, ff2_w, buf_wff1, buf_wff2);
  k_prep_hn<<<dim3(256, 8), 256, 0, stream>>>(buf_high, buf_hst, gnh_s, gnh_b, buf_hn);
  k_hbconv_mfma<<<dim3(4, 32, 8), 256, 0, stream>>>(buf_hn, buf_wbf, hb_b, buf_high, buf_ehigh);

  k_ff1_mfma<<<2048, 256, 0, stream>>>(buf_elow, buf_ehigh, buf_wff1, ff1_b, buf_tbf, buf_ffst);
  k_gnfin<<<1, 32, 0, stream>>>(buf_ffst, 1.f / 786432.f);
  k_ff2_mfma<<<2048, 256, 0, stream>>>(buf_tbf, buf_ffst, gnff_s, gnff_b, buf_wff2, ff2_b,
                                       (float*)d_out);
}